// Round 1
// 699.629 us; speedup vs baseline: 1.0714x; 1.0714x over previous
//
#include <hip/hip_runtime.h>

#define NN   10000
#define NE   160000
#define DIM  240
#define EB   16    // edges per block (edge kernel)
#define NPB  16    // nodes per block (node kernel)

typedef __bf16 bf16x8 __attribute__((ext_vector_type(8)));
typedef __bf16 bf16x4 __attribute__((ext_vector_type(4)));
typedef float  f32x4  __attribute__((ext_vector_type(4)));

__device__ __forceinline__ float sigf(float x) { return 1.0f / (1.0f + __expf(-x)); }

// -------- workspace layout --------
// bf16 B-fragments for mfma_f32_16x16x32_bf16:
//   lane l holds B[k=(l>>4)*8+j][n=l&15], j=0..7, per (nt, ks)
#define OFF_WB1 0        // [Ws|We]: N=272 (17 nt), K=128 (4 ks)
#define OFF_WB2 34816    // W0:      N=112 (7 nt),  K=128 (4 ks)
#define OFF_W1  49152    // so2_W1:  N=32 (2 nt),   K=64  (2 ks)
#define OFF_W2  51200    // so2_W2:  N=16 (1 nt),   K=32  (1 ks)
#define OFF_PW0 51712    // post_W0: N=64 (4 nt),   K=64  (2 ks)
#define OFF_PW1 55808    // post_W1: N=32 (2 nt),   K=32  (1 ks)
#define OFF_PW2 56832    // post_W2: N=16 (1 nt),   K=16 pad 32
#define OHT_BYTE_OFF 131072     // float [96][112]
#define CNT_BYTE_OFF 196608     // int [10240]
#define ROW_BYTE_OFF 237568     // int [10016] (rowptr, 10001 used)
#define CUR_BYTE_OFF 282624     // int [10240]
#define EID_BYTE_OFF 327680     // int [160000]
#define MSG_BYTE_OFF 1048576    // bf16 [NE][240] = 76.8 MB

__global__ __launch_bounds__(256) void prep_kernel(
    const float* __restrict__ Ws, const float* __restrict__ We, const float* __restrict__ W0,
    const float* __restrict__ W1, const float* __restrict__ W2,
    const float* __restrict__ pW0, const float* __restrict__ pW1, const float* __restrict__ pW2,
    const float* __restrict__ w0g, const float* __restrict__ w1g, const float* __restrict__ w2g,
    __bf16* __restrict__ wsb, float* __restrict__ ohT)
{
    int tid = blockIdx.x * 256 + threadIdx.x;
    int stride = gridDim.x * 256;
    for (int idx = tid; idx < 17*4*512; idx += stride) {
        int j = idx & 7, lane = (idx >> 3) & 63, ks = (idx >> 9) & 3, nt = idx >> 11;
        int k = ks*32 + (lane >> 4)*8 + j, n = nt*16 + (lane & 15);
        float v = (n < 160) ? Ws[k*160 + n] : We[k*112 + (n - 160)];
        wsb[OFF_WB1 + idx] = (__bf16)v;
    }
    for (int idx = tid; idx < 7*4*512; idx += stride) {
        int j = idx & 7, lane = (idx >> 3) & 63, ks = (idx >> 9) & 3, nt = idx >> 11;
        int k = ks*32 + (lane >> 4)*8 + j, n = nt*16 + (lane & 15);
        wsb[OFF_WB2 + idx] = (__bf16)W0[k*112 + n];
    }
    for (int idx = tid; idx < 2*2*512; idx += stride) {
        int j = idx & 7, lane = (idx >> 3) & 63, ks = (idx >> 9) & 1, nt = idx >> 10;
        int k = ks*32 + (lane >> 4)*8 + j, n = nt*16 + (lane & 15);
        wsb[OFF_W1 + idx] = (__bf16)W1[k*32 + n];
    }
    for (int idx = tid; idx < 512; idx += stride) {
        int j = idx & 7, lane = (idx >> 3) & 63;
        int k = (lane >> 4)*8 + j, n = lane & 15;
        wsb[OFF_W2 + idx] = (__bf16)W2[k*16 + n];
    }
    for (int idx = tid; idx < 4*2*512; idx += stride) {
        int j = idx & 7, lane = (idx >> 3) & 63, ks = (idx >> 9) & 1, nt = idx >> 10;
        int k = ks*32 + (lane >> 4)*8 + j, n = nt*16 + (lane & 15);
        wsb[OFF_PW0 + idx] = (__bf16)pW0[k*64 + n];
    }
    for (int idx = tid; idx < 2*512; idx += stride) {
        int j = idx & 7, lane = (idx >> 3) & 63, nt = idx >> 9;
        int k = (lane >> 4)*8 + j, n = nt*16 + (lane & 15);
        wsb[OFF_PW1 + idx] = (__bf16)pW1[k*32 + n];
    }
    for (int idx = tid; idx < 512; idx += stride) {
        int j = idx & 7, lane = (idx >> 3) & 63;
        int k = (lane >> 4)*8 + j, n = lane & 15;
        wsb[OFF_PW2 + idx] = (k < 16) ? (__bf16)pW2[k*16 + n] : (__bf16)0.0f;
    }
    for (int idx = tid; idx < 96*112; idx += stride) {
        int k = idx / 112, n2 = idx - k*112;
        float v = 0.f;
        if (k < 95) {
            if (n2 < 64)      v = w0g[n2*95 + k];
            else if (n2 < 96) v = w1g[(n2-64)*95 + k];
            else              v = w2g[(n2-96)*95 + k];
        }
        ohT[idx] = v * 0.10259783521f;
    }
}

// ---------------- CSR build ----------------
__global__ __launch_bounds__(256) void count_kernel(const int* __restrict__ src, int* __restrict__ cnt) {
    int e = blockIdx.x * 256 + threadIdx.x;
    if (e < NE) atomicAdd(&cnt[src[e]], 1);
}

__global__ __launch_bounds__(256) void scan_kernel(const int* __restrict__ cnt,
                                                   int* __restrict__ rowptr, int* __restrict__ cur) {
    __shared__ int part[256];
    int t = threadIdx.x;
    int base = t * 40;
    int local[40];
    int s = 0;
    #pragma unroll
    for (int i = 0; i < 40; i++) {
        int idx = base + i;
        int v = (idx < NN) ? cnt[idx] : 0;
        local[i] = s; s += v;
    }
    part[t] = s;
    __syncthreads();
    for (int off = 1; off < 256; off <<= 1) {
        int v = (t >= off) ? part[t - off] : 0;
        __syncthreads();
        part[t] += v;
        __syncthreads();
    }
    int pre = (t > 0) ? part[t - 1] : 0;
    #pragma unroll
    for (int i = 0; i < 40; i++) {
        int idx = base + i;
        if (idx < NN) { int r = pre + local[i]; rowptr[idx] = r; cur[idx] = r; }
    }
    if (t == 255) rowptr[NN] = part[255];
}

__global__ __launch_bounds__(256) void fill_kernel(const int* __restrict__ src,
                                                   int* __restrict__ cur, int* __restrict__ eidl) {
    int e = blockIdx.x * 256 + threadIdx.x;
    if (e < NE) {
        int slot = atomicAdd(&cur[src[e]], 1);
        eidl[slot] = e;
    }
}

// ---------------- aggregation: gather messages per node ----------------
__global__ __launch_bounds__(256) void agg_kernel(
    const __bf16* __restrict__ msg, const int* __restrict__ rowptr,
    const int* __restrict__ eidl, float* __restrict__ out0)
{
    int wid = threadIdx.x >> 6, lane = threadIdx.x & 63;
    int node = blockIdx.x * 4 + wid;
    if (node >= NN || lane >= 60) return;
    int beg = rowptr[node], end = rowptr[node + 1];
    float a0 = 0.f, a1 = 0.f, a2 = 0.f, a3 = 0.f;
    int i = beg;
    for (; i + 4 <= end; i += 4) {
        int e0 = eidl[i], e1 = eidl[i+1], e2 = eidl[i+2], e3 = eidl[i+3];
        bf16x4 v0 = *(const bf16x4*)(msg + (size_t)e0*240 + lane*4);
        bf16x4 v1 = *(const bf16x4*)(msg + (size_t)e1*240 + lane*4);
        bf16x4 v2 = *(const bf16x4*)(msg + (size_t)e2*240 + lane*4);
        bf16x4 v3 = *(const bf16x4*)(msg + (size_t)e3*240 + lane*4);
        a0 += (float)v0[0] + (float)v1[0] + (float)v2[0] + (float)v3[0];
        a1 += (float)v0[1] + (float)v1[1] + (float)v2[1] + (float)v3[1];
        a2 += (float)v0[2] + (float)v1[2] + (float)v2[2] + (float)v3[2];
        a3 += (float)v0[3] + (float)v1[3] + (float)v2[3] + (float)v3[3];
    }
    for (; i < end; i++) {
        int e = eidl[i];
        bf16x4 v = *(const bf16x4*)(msg + (size_t)e*240 + lane*4);
        a0 += (float)v[0]; a1 += (float)v[1]; a2 += (float)v[2]; a3 += (float)v[3];
    }
    float4 r = { a0, a1, a2, a3 };
    *(float4*)(out0 + (size_t)node*240 + lane*4) = r;
}

// ---------------------------------------------------------------------------
// Edge kernel (MFMA). Restructured:
//  - Wigner rotation collapsed: out = E·(channel ops)·v with E = D·D,
//    applied ONCE at T3b (32/16 ch) — forward rotation (T0b) deleted.
//  - v1/v2 staged component-major (vt1[e][i][64], vt2[e][z][32]) so MFMA
//    A-fragments and T3b reads are single ds_read_b128s.
//  - 4 barriers (was 7). LDS 39936 B -> 4 blocks/CU.
// ---------------------------------------------------------------------------
__global__ __launch_bounds__(256, 4) void edge_mfma_kernel(
    const float* __restrict__ nf, const float* __restrict__ ef,
    const float* __restrict__ latg, const float* __restrict__ D1g, const float* __restrict__ D2g,
    const float* __restrict__ pb0, const int* __restrict__ srcg,
    const __bf16* __restrict__ wsb, float* agg, __bf16* __restrict__ msgout)
{
    __shared__ __align__(16) unsigned char pool[39936];
    __bf16* Cb   = (__bf16*)(pool + 0);       // [16][392]      T1 -> T4
    __bf16* aLat = (__bf16*)(pool + 12544);   // [4][64][8]     T0 -> T1
    __bf16* aSin = (__bf16*)(pool + 16640);   // [4][64][8]     T0 -> T1
    __bf16* v1m  = (__bf16*)(pool + 12544);   // [48][40]       T2 -> T3b (alias aLat)
    __bf16* v2m  = (__bf16*)(pool + 16384);   // [80][24]       T2 -> T3b (alias aSin)
    __bf16* vt1  = (__bf16*)(pool + 20736);   // [16]x(stride 200): [3][64]  T0 -> T2
    __bf16* vt2  = (__bf16*)(pool + 27136);   // [16]x(stride 168): [5][32]  T0 -> T2
    __bf16* aV1g = (__bf16*)(pool + 20736);   // [3][64][8]     T3b -> T4 (alias vt1)
    __bf16* aV2g = (__bf16*)(pool + 23808);   // [5][64][8]     T3b -> T4 (alias vt1/vt2)
    float*  d1s  = (float*)(pool + 32512);    // [144]  raw D1  T0 -> T1
    float*  d2s  = (float*)(pool + 33088);    // [400]  raw D2  T0 -> T1
    float*  gts  = (float*)(pool + 32512);    // [16][49] f32   T2ph -> T3b (alias d1s/d2s)
    __bf16* aSact= (__bf16*)(pool + 35648);   // [2][64][8]     T2ph -> T4
    float*  e1s  = (float*)(pool + 37696);    // [144]  E1=D1·D1  T1 -> T3b
    float*  e2s  = (float*)(pool + 38272);    // [400]  E2=D2·D2  T1 -> T3b

    const int t    = threadIdx.x;
    const int wid  = t >> 6, lane = t & 63;
    const int e0   = blockIdx.x * EB;

    // ---- T0: staging (no srcs barrier: 16 src ids = one L1 line) ----
    for (int idx = t; idx < 144; idx += 256) d1s[idx] = D1g[e0*9  + idx];
    for (int idx = t; idx < 400; idx += 256) d2s[idx] = D2g[e0*25 + idx];
    {
        // vt1: 256 tasks, each = 12 consecutive floats (4 v1 channels), 3 bf16x4 writes
        int e = t >> 4, half = (t >> 3) & 1, cq = t & 7;
        const float* base = half ? (ef + (size_t)(e0 + e)*240 + 64 + cq*12)
                                 : (nf + (size_t)srcg[e0 + e]*240 + 64 + cq*12);
        float4 f0 = *(const float4*)base;
        float4 f1 = *(const float4*)(base + 4);
        float4 f2 = *(const float4*)(base + 8);
        float f[12] = {f0.x,f0.y,f0.z,f0.w,f1.x,f1.y,f1.z,f1.w,f2.x,f2.y,f2.z,f2.w};
        int c = half*32 + cq*4;
        __bf16* dst = vt1 + e*200 + c;
        #pragma unroll
        for (int i = 0; i < 3; i++) {
            bf16x4 v = {(__bf16)f[i], (__bf16)f[3+i], (__bf16)f[6+i], (__bf16)f[9+i]};
            *(bf16x4*)(dst + i*64) = v;
        }
    }
    if (t < 128) {
        // vt2: 128 tasks, each = 20 consecutive floats (4 v2 channels), 5 bf16x4 writes
        int e = t >> 3, half = (t >> 2) & 1, cq = t & 3;
        const float* base = half ? (ef + (size_t)(e0 + e)*240 + 160 + cq*20)
                                 : (nf + (size_t)srcg[e0 + e]*240 + 160 + cq*20);
        float f[20];
        #pragma unroll
        for (int k = 0; k < 5; k++) {
            float4 q4 = *(const float4*)(base + k*4);
            f[4*k] = q4.x; f[4*k+1] = q4.y; f[4*k+2] = q4.z; f[4*k+3] = q4.w;
        }
        int c = half*16 + cq*4;
        __bf16* dst = vt2 + e*168 + c;
        #pragma unroll
        for (int z = 0; z < 5; z++) {
            bf16x4 v = {(__bf16)f[z], (__bf16)f[5+z], (__bf16)f[10+z], (__bf16)f[15+z]};
            *(bf16x4*)(dst + z*32) = v;
        }
    }
    {
        int ks = t >> 6, l2 = t & 63, e = l2 & 15;
        int k0 = ks*32 + (l2 >> 4)*8;
        {
            const float4* p4 = (const float4*)(latg + (size_t)(e0 + e)*128 + k0);
            float4 f0 = p4[0], f1 = p4[1];
            bf16x8 v;
            v[0]=(__bf16)f0.x; v[1]=(__bf16)f0.y; v[2]=(__bf16)f0.z; v[3]=(__bf16)f0.w;
            v[4]=(__bf16)f1.x; v[5]=(__bf16)f1.y; v[6]=(__bf16)f1.z; v[7]=(__bf16)f1.w;
            *(bf16x8*)(aLat + t*8) = v;
        }
        {
            const float* s2 = (k0 < 64) ? (nf + (size_t)srcg[e0 + e]*240 + k0)
                                        : (ef + (size_t)(e0 + e)*240 + (k0 - 64));
            const float4* p4 = (const float4*)s2;
            float4 f0 = p4[0], f1 = p4[1];
            bf16x8 v;
            v[0]=(__bf16)f0.x; v[1]=(__bf16)f0.y; v[2]=(__bf16)f0.z; v[3]=(__bf16)f0.w;
            v[4]=(__bf16)f1.x; v[5]=(__bf16)f1.y; v[6]=(__bf16)f1.z; v[7]=(__bf16)f1.w;
            *(bf16x8*)(aSin + t*8) = v;
        }
    }
    __syncthreads();

    // ---- T1: GEMM1 + E = D·D matrices ----
    {
        int col16 = lane & 15, ebase = (lane >> 4)*4;
        bf16x8 aL[4], aS[4];
        #pragma unroll
        for (int ks = 0; ks < 4; ks++) {
            aL[ks] = *(const bf16x8*)(aLat + (ks*64 + lane)*8);
            aS[ks] = *(const bf16x8*)(aSin + (ks*64 + lane)*8);
        }
        #pragma unroll
        for (int it = 0; it < 6; it++) {
            int nt = wid + it*4;
            bool isLat = nt < 17;
            const __bf16* bB = isLat ? (wsb + OFF_WB1 + nt*2048)
                                     : (wsb + OFF_WB2 + (nt - 17)*2048);
            f32x4 acc = {0.f, 0.f, 0.f, 0.f};
            #pragma unroll
            for (int ks = 0; ks < 4; ks++) {
                bf16x8 b = *(const bf16x8*)(bB + (ks*64 + lane)*8);
                acc = __builtin_amdgcn_mfma_f32_16x16x32_bf16(isLat ? aL[ks] : aS[ks], b, acc, 0, 0, 0);
            }
            int col = (isLat ? nt*16 : 272 + (nt - 17)*16) + col16;
            #pragma unroll
            for (int r = 0; r < 4; r++) Cb[(ebase + r)*392 + col] = (__bf16)acc[r];
        }
    }
    // E1[e][i][k] = sum_t D1[i][t] D1[t][k];  E2 likewise (5x5)
    for (int idx = t; idx < 544; idx += 256) {
        if (idx < 144) {
            int e = idx / 9, r = idx - e*9, i = r / 3, k = r - i*3;
            const float* d = d1s + e*9;
            e1s[idx] = d[i*3+0]*d[0*3+k] + d[i*3+1]*d[1*3+k] + d[i*3+2]*d[2*3+k];
        } else {
            int j = idx - 144;
            int e = j / 25, r = j - e*25, i = r / 5, k = r - i*5;
            const float* d = d2s + e*25;
            float a = 0.f;
            #pragma unroll
            for (int tt = 0; tt < 5; tt++) a += d[i*5+tt] * d[tt*5+k];
            e2s[j] = a;
        }
    }
    __syncthreads();

    // ---- T2: v GEMMs on UNROTATED inputs (A-frags = b128 reads from vt) ----
    {
        int col16 = lane & 15, er = lane & 15, q8 = (lane >> 4)*8, ebase = (lane >> 4)*4;
        for (int p = wid; p < 11; p += 4) {
            f32x4 acc = {0.f, 0.f, 0.f, 0.f};
            if (p < 6) {
                int i = p >> 1, nt = p & 1;
                #pragma unroll
                for (int ks = 0; ks < 2; ks++) {
                    bf16x8 a = *(const bf16x8*)(vt1 + er*200 + i*64 + ks*32 + q8);
                    bf16x8 b = *(const bf16x8*)(wsb + OFF_W1 + ((nt*2 + ks)*64 + lane)*8);
                    acc = __builtin_amdgcn_mfma_f32_16x16x32_bf16(a, b, acc, 0, 0, 0);
                }
                int col = nt*16 + col16;
                #pragma unroll
                for (int r = 0; r < 4; r++) v1m[(i*16 + ebase + r)*40 + col] = (__bf16)acc[r];
            } else {
                int i = p - 6;
                bf16x8 a = *(const bf16x8*)(vt2 + er*168 + i*32 + q8);
                bf16x8 b = *(const bf16x8*)(wsb + OFF_W2 + lane*8);
                acc = __builtin_amdgcn_mfma_f32_16x16x32_bf16(a, b, acc, 0, 0, 0);
                #pragma unroll
                for (int r = 0; r < 4; r++) v2m[(i*16 + ebase + r)*24 + col16] = (__bf16)acc[r];
            }
        }
    }
    // ---- T3a (same phase — independent of T2): s_act A-frag + gates ----
    if (t < 128) {
        int ks = t >> 6, l2 = t & 63, e = l2 & 15, o0 = ks*32 + (l2 >> 4)*8;
        bf16x8 v;
        #pragma unroll
        for (int j = 0; j < 8; j++) {
            int o = o0 + j;
            float x = (float)Cb[e*392 + 272 + o] * (float)Cb[e*392 + o];
            v[j] = (__bf16)(x * sigf(x));
        }
        *(bf16x8*)(aSact + t*8) = v;
    }
    for (int idx = t; idx < 768; idx += 256) {
        int e = idx / 48, o = idx - e*48;
        float x = (float)Cb[e*392 + 336 + o] * (float)Cb[e*392 + 64 + o];
        gts[e*49 + o] = sigf(x);
    }
    __syncthreads();

    // ---- T3b: single E-rotation + scale + gate -> A-frags (all b128 reads) ----
    for (int idx = t; idx < 512; idx += 256) {
        if (idx < 192) {
            int i = idx >> 6, l2 = idx & 63, e = l2 & 15, c0 = (l2 >> 4)*8;
            float z0 = e1s[e*9 + i*3], z1 = e1s[e*9 + i*3 + 1], z2 = e1s[e*9 + i*3 + 2];
            bf16x8 m0 = *(const bf16x8*)(v1m + (0*16 + e)*40 + c0);
            bf16x8 m1 = *(const bf16x8*)(v1m + (1*16 + e)*40 + c0);
            bf16x8 m2 = *(const bf16x8*)(v1m + (2*16 + e)*40 + c0);
            bf16x8 s8 = *(const bf16x8*)(Cb + e*392 + 112 + c0);
            bf16x8 v;
            #pragma unroll
            for (int j = 0; j < 8; j++) {
                float g = gts[e*49 + c0 + j];
                float a = z0*(float)m0[j] + z1*(float)m1[j] + z2*(float)m2[j];
                v[j] = (__bf16)(g * (float)s8[j] * a);
            }
            *(bf16x8*)(aV1g + idx*8) = v;
        } else {
            int idx2 = idx - 192;
            int i = idx2 >> 6, l2 = idx2 & 63, e = l2 & 15, c0 = (l2 >> 4)*8;
            bf16x8 v;
            if (c0 < 16) {
                const float* ee = e2s + e*25 + i*5;
                float z0 = ee[0], z1 = ee[1], z2 = ee[2], z3 = ee[3], z4 = ee[4];
                bf16x8 m0 = *(const bf16x8*)(v2m + (0*16 + e)*24 + c0);
                bf16x8 m1 = *(const bf16x8*)(v2m + (1*16 + e)*24 + c0);
                bf16x8 m2 = *(const bf16x8*)(v2m + (2*16 + e)*24 + c0);
                bf16x8 m3 = *(const bf16x8*)(v2m + (3*16 + e)*24 + c0);
                bf16x8 m4 = *(const bf16x8*)(v2m + (4*16 + e)*24 + c0);
                bf16x8 s8 = *(const bf16x8*)(Cb + e*392 + 144 + c0);
                #pragma unroll
                for (int j = 0; j < 8; j++) {
                    float g = gts[e*49 + 32 + c0 + j];
                    float a = z0*(float)m0[j] + z1*(float)m1[j] + z2*(float)m2[j]
                            + z3*(float)m3[j] + z4*(float)m4[j];
                    v[j] = (__bf16)(g * (float)s8[j] * a);
                }
            } else {
                #pragma unroll
                for (int j = 0; j < 8; j++) v[j] = (__bf16)0.0f;
            }
            *(bf16x8*)(aV2g + idx2*8) = v;
        }
    }
    __syncthreads();

    // ---- T4: post GEMMs, env scale, message write (or atomic fallback) ----
    {
        int col16 = lane & 15, ebase = (lane >> 4)*4;
        for (int p = wid; p < 15; p += 4) {
            f32x4 acc = {0.f, 0.f, 0.f, 0.f};
            if (p < 4) {
                int nt = p;
                #pragma unroll
                for (int ks = 0; ks < 2; ks++) {
                    bf16x8 a = *(const bf16x8*)(aSact + (ks*64 + lane)*8);
                    bf16x8 b = *(const bf16x8*)(wsb + OFF_PW0 + ((nt*2 + ks)*64 + lane)*8);
                    acc = __builtin_amdgcn_mfma_f32_16x16x32_bf16(a, b, acc, 0, 0, 0);
                }
                int o = nt*16 + col16;
                float bias = pb0[o];
                #pragma unroll
                for (int r = 0; r < 4; r++) {
                    int e = ebase + r;
                    float val = (acc[r] + bias) * (float)Cb[e*392 + 160 + o];
                    if (msgout) msgout[(size_t)(e0 + e)*240 + o] = (__bf16)val;
                    else        atomicAdd(agg + (size_t)srcg[e0 + e]*240 + o, val);
                }
            } else if (p < 10) {
                int q = p - 4, i = q >> 1, nt = q & 1;
                bf16x8 a = *(const bf16x8*)(aV1g + (i*64 + lane)*8);
                bf16x8 b = *(const bf16x8*)(wsb + OFF_PW1 + (nt*64 + lane)*8);
                acc = __builtin_amdgcn_mfma_f32_16x16x32_bf16(a, b, acc, 0, 0, 0);
                int o = nt*16 + col16;
                #pragma unroll
                for (int r = 0; r < 4; r++) {
                    int e = ebase + r;
                    float val = acc[r] * (float)Cb[e*392 + 224 + o];
                    if (msgout) msgout[(size_t)(e0 + e)*240 + 64 + o*3 + i] = (__bf16)val;
                    else        atomicAdd(agg + (size_t)srcg[e0 + e]*240 + 64 + o*3 + i, val);
                }
            } else {
                int i = p - 10;
                bf16x8 a = *(const bf16x8*)(aV2g + (i*64 + lane)*8);
                bf16x8 b = *(const bf16x8*)(wsb + OFF_PW2 + lane*8);
                acc = __builtin_amdgcn_mfma_f32_16x16x32_bf16(a, b, acc, 0, 0, 0);
                #pragma unroll
                for (int r = 0; r < 4; r++) {
                    int e = ebase + r;
                    float val = acc[r] * (float)Cb[e*392 + 256 + col16];
                    if (msgout) msgout[(size_t)(e0 + e)*240 + 160 + col16*5 + i] = (__bf16)val;
                    else        atomicAdd(agg + (size_t)srcg[e0 + e]*240 + 160 + col16*5 + i, val);
                }
            }
        }
    }
}

// ---------------------------------------------------------------------------
// Node kernel (unchanged)
// ---------------------------------------------------------------------------
__global__ __launch_bounds__(256, 2) void node_kernel(
    const float* __restrict__ nf, const float* __restrict__ mcplg,
    const float* __restrict__ ohg,
    const float* __restrict__ cW1, const float* __restrict__ cb1,
    const float* __restrict__ cW2, const float* __restrict__ cb2,
    const float* __restrict__ gsW, const float* __restrict__ gsb,
    const float* __restrict__ mW1, const float* __restrict__ mb1,
    const float* __restrict__ mW2, const float* __restrict__ mb2,
    const float* __restrict__ lng, const float* __restrict__ lnb,
    const float* __restrict__ rW0, const float* __restrict__ rb0,
    const float* __restrict__ rW1, const float* __restrict__ rW2,
    const float* __restrict__ ohT, float* out0, float* out1)
{
    __shared__ __align__(16) unsigned char pool[68608];
    float* mcp  = (float*)(pool + 0);      // [16][128]
    float* ohv  = (float*)(pool + 8192);   // [16][96]
    float* nsr  = (float*)(pool + 14336);  // [16][240]
    float* anew = (float*)(pool + 29696);  // [16][240]
    float* t12  = (float*)(pool + 45056);  // [16][128]
    float* cfg  = (float*)(pool + 53248);  // [16][112]
    float* scm  = (float*)(pool + 60416);  // [16][128]

    const int t  = threadIdx.x;
    const int g  = t >> 7;
    const int o  = t & 127;
    const int nb = g * 8;
    const int n0 = blockIdx.x * NPB;

    for (int idx = t; idx < NPB * 128; idx += 256) {
        int n = idx >> 7, k = idx & 127;
        mcp[n*128 + k] = mcplg[(n0 + n) * 128 + k];
    }
    for (int idx = t; idx < NPB * 96; idx += 256) {
        int n = idx / 96, k = idx - n * 96;
        ohv[n*96 + k] = (k < 95) ? ohg[(n0 + n) * 95 + k] : 0.f;
    }
    for (int idx = t; idx < NPB * 240; idx += 256) {
        int n = idx / 240, k = idx - n * 240;
        nsr[n*240 + k]  = nf[(n0 + n) * DIM + k];
        anew[n*240 + k] = out0[(n0 + n) * DIM + k];
    }
    __syncthreads();

    {
        float a[8]; float b = cb1[o];
        #pragma unroll
        for (int i = 0; i < 8; i++) a[i] = b;
        #pragma unroll 2
        for (int k4 = 0; k4 < 32; k4++) {
            float w0 = cW1[(4*k4+0)*128 + o], w1 = cW1[(4*k4+1)*128 + o],
                  w2 = cW1[(4*k4+2)*128 + o], w3 = cW1[(4*k4+3)*128 + o];
            #pragma unroll
            for (int i = 0; i < 8; i++) {
                float4 m = *(const float4*)&mcp[(nb+i)*128 + 4*k4];
                a[i] += m.x*w0 + m.y*w1 + m.z*w2 + m.w*w3;
            }
        }
        #pragma unroll
        for (int i = 0; i < 8; i++) { float x = a[i]; t12[(nb+i)*128 + o] = x * sigf(x); }
    }
    __syncthreads();

    if (o < 112) {
        float a[8]; float b = cb2[o];
        #pragma unroll
        for (int i = 0; i < 8; i++) a[i] = b;
        #pragma unroll 2
        for (int k4 = 0; k4 < 32; k4++) {
            float w0 = cW2[(4*k4+0)*112 + o], w1 = cW2[(4*k4+1)*112 + o],
                  w2 = cW2[(4*k4+2)*112 + o], w3 = cW2[(4*k4+3)*112 + o];
            #pragma unroll
            for (int i = 0; i < 8; i++) {
                float4 m = *(const float4*)&t12[(nb+i)*128 + 4*k4];
                a[i] += m.x*w0 + m.y*w1 + m.z*w2 + m.w*w3;
            }
        }
        #pragma unroll
        for (int i = 0; i < 8; i++) cfg[(nb+i)*112 + o] = a[i];
    }
    __syncthreads();

    for (int idx = t; idx < NPB * 240; idx += 256) {
        int n = idx / 240, d = idx - n * 240;
        int ch = (d < 64) ? d : (d < 160 ? 64 + (d - 64) / 3 : 96 + (d - 160) / 5);
        anew[n*240 + d] *= 0.25f * cfg[n*112 + ch];
    }
    __syncthreads();

    {
        float a[8]; float b = gsb[o];
        #pragma unroll
        for (int i = 0; i < 8; i++) a[i] = b;
        #pragma unroll 2
        for (int k4 = 0; k4 < 16; k4++) {
            float w0 = gsW[(4*k4+0)*128 + o], w1 = gsW[(4*k4+1)*128 + o],
                  w2 = gsW[(4*k4+2)*128 + o], w3 = gsW[(4*k4+3)*128 + o];
            #pragma unroll
            for (int i = 0; i < 8; i++) {
                float4 m = *(const float4*)&anew[(nb+i)*240 + 4*k4];
                a[i] += m.x*w0 + m.y*w1 + m.z*w2 + m.w*w3;
            }
        }
        #pragma unroll
        for (int i = 0; i < 8; i++) scm[(nb+i)*128 + o] = a[i];
    }
    __syncthreads();

    {
        float a[8]; float b = mb1[o];
        #pragma unroll
        for (int i = 0; i < 8; i++) a[i] = b;
        #pragma unroll 2
        for (int k4 = 0; k4 < 32; k4++) {
            float w0 = mW1[(4*k4+0)*128 + o], w1 = mW1[(4*k4+1)*128 + o],
                  w2 = mW1[(4*k4+2)*128 + o], w3 = mW1[(4*k4+3)*128 + o];
            #pragma unroll
            for (int i = 0; i < 8; i++) {
                float4 m = *(const float4*)&scm[(nb+i)*128 + 4*k4];
                a[i] += m.x*w0 + m.y*w1 + m.z*w2 + m.w*w3;
            }
        }
        #pragma unroll 2
        for (int k4 = 0; k4 < 32; k4++) {
            float w0 = mW1[(128+4*k4+0)*128 + o], w1 = mW1[(128+4*k4+1)*128 + o],
                  w2 = mW1[(128+4*k4+2)*128 + o], w3 = mW1[(128+4*k4+3)*128 + o];
            #pragma unroll
            for (int i = 0; i < 8; i++) {
                float4 m = *(const float4*)&mcp[(nb+i)*128 + 4*k4];
                a[i] += m.x*w0 + m.y*w1 + m.z*w2 + m.w*w3;
            }
        }
        #pragma unroll
        for (int i = 0; i < 8; i++) { float x = a[i]; t12[(nb+i)*128 + o] = x * sigf(x); }
    }
    __syncthreads();

    {
        float a[8]; float b = mb2[o];
        #pragma unroll
        for (int i = 0; i < 8; i++) a[i] = b;
        #pragma unroll 2
        for (int k4 = 0; k4 < 32; k4++) {
            float w0 = mW2[(4*k4+0)*128 + o], w1 = mW2[(4*k4+1)*128 + o],
                  w2 = mW2[(4*k4+2)*128 + o], w3 = mW2[(4*k4+3)*128 + o];
            #pragma unroll
            for (int i = 0; i < 8; i++) {
                float4 m = *(const float4*)&t12[(nb+i)*128 + 4*k4];
                a[i] += m.x*w0 + m.y*w1 + m.z*w2 + m.w*w3;
            }
        }
        #pragma unroll
        for (int i = 0; i < 8; i++) scm[(nb+i)*128 + o] = mcp[(nb+i)*128 + o] + a[i];
    }
    __syncthreads();

    {
        int n = t >> 4, l = t & 15;
        float x[8]; float s = 0.f, ss = 0.f;
        #pragma unroll
        for (int i = 0; i < 8; i++) { x[i] = scm[n*128 + l + 16*i]; s += x[i]; ss += x[i]*x[i]; }
        #pragma unroll
        for (int off = 8; off > 0; off >>= 1) {
            s  += __shfl_down(s,  off, 16);
            ss += __shfl_down(ss, off, 16);
        }
        s  = __shfl(s, 0, 16);
        ss = __shfl(ss, 0, 16);
        float mu   = s * (1.f / 128.f);
        float var  = ss * (1.f / 128.f) - mu * mu;
        float rstd = rsqrtf(var + 1e-5f);
        float* op = out1 + (n0 + n) * 128;
        #pragma unroll
        for (int i = 0; i < 8; i++) {
            int c = l + 16*i;
            op[c] = (x[i] - mu) * rstd * lng[c] + lnb[c];
        }
    }

    if (o < 112) {
        float a[8] = {0.f,0.f,0.f,0.f,0.f,0.f,0.f,0.f};
        #pragma unroll 2
        for (int k4 = 0; k4 < 24; k4++) {
            float w0 = ohT[(4*k4+0)*112 + o], w1 = ohT[(4*k4+1)*112 + o],
                  w2 = ohT[(4*k4+2)*112 + o], w3 = ohT[(4*k4+3)*112 + o];
            #pragma unroll
            for (int i = 0; i < 8; i++) {
                float4 m = *(const float4*)&ohv[(nb+i)*96 + 4*k4];
                a[i] += m.x*w0 + m.y*w1 + m.z*w2 + m.w*w3;
            }
        }
        #pragma unroll
        for (int i = 0; i < 8; i++) cfg[(nb+i)*112 + o] = a[i];
    }
    __syncthreads();

    const float c_new = 0.4472135955f;
    const float c_old = 0.8944271910f;
    for (int idx = t; idx < NPB * 240; idx += 256) {
        int n = idx / 240, d = idx - n * 240;
        float res, gg;
        if (d < 64) {
            float acc = rb0[d];
            #pragma unroll 4
            for (int c = 0; c < 64; c++) acc += nsr[n*240 + c] * rW0[c * 64 + d];
            res = acc; gg = cfg[n*112 + d];
        } else if (d < 160) {
            int dd = d - 64, oo = dd / 3, j = dd - oo * 3;
            float acc = 0.f;
            #pragma unroll 4
            for (int c = 0; c < 32; c++) acc += nsr[n*240 + 64 + c*3 + j] * rW1[c * 32 + oo];
            res = acc; gg = cfg[n*112 + 64 + oo];
        } else {
            int dd = d - 160, oo = dd / 5, j = dd - oo * 5;
            float acc = 0.f;
            #pragma unroll 4
            for (int c = 0; c < 16; c++) acc += nsr[n*240 + 160 + c*5 + j] * rW2[c * 16 + oo];
            res = acc; gg = cfg[n*112 + 96 + oo];
        }
        float v = c_new * anew[n*240 + d] + c_old * res;
        out0[(n0 + n) * DIM + d] = v * (1.f + gg);
    }
}

extern "C" void kernel_launch(void* const* d_in, const int* in_sizes, int n_in,
                              void* d_out, int out_size, void* d_ws, size_t ws_size,
                              hipStream_t stream) {
    const float* nf      = (const float*)d_in[0];
    const float* ef      = (const float*)d_in[1];
    const float* lat     = (const float*)d_in[2];
    const float* mcpl    = (const float*)d_in[3];
    const float* ohot    = (const float*)d_in[4];
    const float* D1      = (const float*)d_in[5];
    const float* D2      = (const float*)d_in[6];
    const float* so2_W0  = (const float*)d_in[7];
    const float* so2_W1  = (const float*)d_in[8];
    const float* so2_W2  = (const float*)d_in[9];
    const float* so2_Ws  = (const float*)d_in[10];
    const float* env_W   = (const float*)d_in[11];
    const float* post_W0 = (const float*)d_in[12];
    const float* post_b0 = (const float*)d_in[13];
    const float* post_W1 = (const float*)d_in[14];
    const float* post_W2 = (const float*)d_in[15];
    const float* res_W0  = (const float*)d_in[16];
    const float* res_b0  = (const float*)d_in[17];
    const float* res_W1  = (const float*)d_in[18];
    const float* res_W2  = (const float*)d_in[19];
    const float* cpl_W1  = (const float*)d_in[20];
    const float* cpl_b1  = (const float*)d_in[21];
    const float* cpl_W2  = (const float*)d_in[22];
    const float* cpl_b2  = (const float*)d_in[23];
    const float* gs_W    = (const float*)d_in[24];
    const float* gs_b    = (const float*)d_in[25];
    const float* msg_W1  = (const float*)d_in[26];
    const float* msg_b1  = (const float*)d_in[27];
    const float* msg_W2  = (const float*)d_in[28];
    const float* msg_b2  = (const float*)d_in[29];
    const float* ln_g    = (const float*)d_in[30];
    const float* ln_b    = (const float*)d_in[31];
    const float* oh_w0   = (const float*)d_in[32];
    const float* oh_w1   = (const float*)d_in[33];
    const float* oh_w2   = (const float*)d_in[34];
    const int*   eidx    = (const int*)d_in[35];   // (2,E); row 0 = src

    float* out0 = (float*)d_out;                     // N*DIM, doubles as agg
    float* out1 = (float*)d_out + (size_t)NN * DIM;  // N*CPL
    char*   wsB = (char*)d_ws;
    __bf16* wsb = (__bf16*)d_ws;
    float*  ohT = (float*)(wsB + OHT_BYTE_OFF);

    const size_t need = (size_t)MSG_BYTE_OFF + (size_t)NE * 240 * 2;
    const bool planA = ws_size >= need;

    (void)hipMemsetAsync(out0, 0, (size_t)NN * DIM * sizeof(float), stream);

    prep_kernel<<<56, 256, 0, stream>>>(so2_Ws, env_W, so2_W0, so2_W1, so2_W2,
                                        post_W0, post_W1, post_W2,
                                        oh_w0, oh_w1, oh_w2, wsb, ohT);

    if (planA) {
        int*    cnt  = (int*)(wsB + CNT_BYTE_OFF);
        int*    row  = (int*)(wsB + ROW_BYTE_OFF);
        int*    cur  = (int*)(wsB + CUR_BYTE_OFF);
        int*    eidl = (int*)(wsB + EID_BYTE_OFF);
        __bf16* msg  = (__bf16*)(wsB + MSG_BYTE_OFF);

        (void)hipMemsetAsync(cnt, 0, 10240 * sizeof(int), stream);
        count_kernel<<<(NE + 255) / 256, 256, 0, stream>>>(eidx, cnt);
        scan_kernel<<<1, 256, 0, stream>>>(cnt, row, cur);
        fill_kernel<<<(NE + 255) / 256, 256, 0, stream>>>(eidx, cur, eidl);

        edge_mfma_kernel<<<NE / EB, 256, 0, stream>>>(
            nf, ef, lat, D1, D2, post_b0, eidx, wsb, out0, msg);

        agg_kernel<<<(NN + 3) / 4, 256, 0, stream>>>(msg, row, eidl, out0);
    } else {
        edge_mfma_kernel<<<NE / EB, 256, 0, stream>>>(
            nf, ef, lat, D1, D2, post_b0, eidx, wsb, out0, nullptr);
    }

    node_kernel<<<NN / NPB, 256, 0, stream>>>(
        nf, mcpl, ohot, cpl_W1, cpl_b1, cpl_W2, cpl_b2, gs_W, gs_b,
        msg_W1, msg_b1, msg_W2, msg_b2, ln_g, ln_b,
        res_W0, res_b0, res_W1, res_W2, ohT, out0, out1);
}

// Round 2
// 695.330 us; speedup vs baseline: 1.0781x; 1.0062x over previous
//
#include <hip/hip_runtime.h>

#define NN   10000
#define NE   160000
#define DIM  240
#define EB   16    // edges per block (edge kernel)
#define NPB  16    // nodes per block (node kernel)

typedef __bf16 bf16x8 __attribute__((ext_vector_type(8)));
typedef __bf16 bf16x4 __attribute__((ext_vector_type(4)));
typedef float  f32x4  __attribute__((ext_vector_type(4)));

__device__ __forceinline__ float sigf(float x) { return 1.0f / (1.0f + __expf(-x)); }

// -------- workspace layout --------
// bf16 B-fragments for mfma_f32_16x16x32_bf16:
//   lane l holds B[k=(l>>4)*8+j][n=l&15], j=0..7, per (nt, ks)
#define OFF_WB1 0        // [Ws|We]: N=272 (17 nt), K=128 (4 ks)
#define OFF_WB2 34816    // W0:      N=112 (7 nt),  K=128 (4 ks)
#define OFF_W1  49152    // so2_W1:  N=32 (2 nt),   K=64  (2 ks)
#define OFF_W2  51200    // so2_W2:  N=16 (1 nt),   K=32  (1 ks)
#define OFF_PW0 51712    // post_W0: N=64 (4 nt),   K=64  (2 ks)
#define OFF_PW1 55808    // post_W1: N=32 (2 nt),   K=32  (1 ks)
#define OFF_PW2 56832    // post_W2: N=16 (1 nt),   K=16 pad 32
#define OHT_BYTE_OFF 131072     // float [96][112]
#define CNT_BYTE_OFF 196608     // int [10240]
#define ROW_BYTE_OFF 237568     // int [10016] (rowptr, 10001 used)
#define CUR_BYTE_OFF 282624     // int [10240]
#define EID_BYTE_OFF 327680     // int [160000]

__global__ __launch_bounds__(256) void prep_kernel(
    const float* __restrict__ Ws, const float* __restrict__ We, const float* __restrict__ W0,
    const float* __restrict__ W1, const float* __restrict__ W2,
    const float* __restrict__ pW0, const float* __restrict__ pW1, const float* __restrict__ pW2,
    const float* __restrict__ w0g, const float* __restrict__ w1g, const float* __restrict__ w2g,
    __bf16* __restrict__ wsb, float* __restrict__ ohT,
    const int* __restrict__ src, int* __restrict__ cnt)
{
    // blocks >= 56: edge-count duty (merged count_kernel)
    if (blockIdx.x >= 56) {
        if (cnt) {
            int e = (blockIdx.x - 56) * 256 + threadIdx.x;
            if (e < NE) atomicAdd(&cnt[src[e]], 1);
        }
        return;
    }
    int tid = blockIdx.x * 256 + threadIdx.x;
    const int stride = 56 * 256;
    for (int idx = tid; idx < 17*4*512; idx += stride) {
        int j = idx & 7, lane = (idx >> 3) & 63, ks = (idx >> 9) & 3, nt = idx >> 11;
        int k = ks*32 + (lane >> 4)*8 + j, n = nt*16 + (lane & 15);
        float v = (n < 160) ? Ws[k*160 + n] : We[k*112 + (n - 160)];
        wsb[OFF_WB1 + idx] = (__bf16)v;
    }
    for (int idx = tid; idx < 7*4*512; idx += stride) {
        int j = idx & 7, lane = (idx >> 3) & 63, ks = (idx >> 9) & 3, nt = idx >> 11;
        int k = ks*32 + (lane >> 4)*8 + j, n = nt*16 + (lane & 15);
        wsb[OFF_WB2 + idx] = (__bf16)W0[k*112 + n];
    }
    for (int idx = tid; idx < 2*2*512; idx += stride) {
        int j = idx & 7, lane = (idx >> 3) & 63, ks = (idx >> 9) & 1, nt = idx >> 10;
        int k = ks*32 + (lane >> 4)*8 + j, n = nt*16 + (lane & 15);
        wsb[OFF_W1 + idx] = (__bf16)W1[k*32 + n];
    }
    for (int idx = tid; idx < 512; idx += stride) {
        int j = idx & 7, lane = (idx >> 3) & 63;
        int k = (lane >> 4)*8 + j, n = lane & 15;
        wsb[OFF_W2 + idx] = (__bf16)W2[k*16 + n];
    }
    for (int idx = tid; idx < 4*2*512; idx += stride) {
        int j = idx & 7, lane = (idx >> 3) & 63, ks = (idx >> 9) & 1, nt = idx >> 10;
        int k = ks*32 + (lane >> 4)*8 + j, n = nt*16 + (lane & 15);
        wsb[OFF_PW0 + idx] = (__bf16)pW0[k*64 + n];
    }
    for (int idx = tid; idx < 2*512; idx += stride) {
        int j = idx & 7, lane = (idx >> 3) & 63, nt = idx >> 9;
        int k = (lane >> 4)*8 + j, n = nt*16 + (lane & 15);
        wsb[OFF_PW1 + idx] = (__bf16)pW1[k*32 + n];
    }
    for (int idx = tid; idx < 512; idx += stride) {
        int j = idx & 7, lane = (idx >> 3) & 63;
        int k = (lane >> 4)*8 + j, n = lane & 15;
        wsb[OFF_PW2 + idx] = (k < 16) ? (__bf16)pW2[k*16 + n] : (__bf16)0.0f;
    }
    for (int idx = tid; idx < 96*112; idx += stride) {
        int k = idx / 112, n2 = idx - k*112;
        float v = 0.f;
        if (k < 95) {
            if (n2 < 64)      v = w0g[n2*95 + k];
            else if (n2 < 96) v = w1g[(n2-64)*95 + k];
            else              v = w2g[(n2-96)*95 + k];
        }
        ohT[idx] = v * 0.10259783521f;
    }
}

// ---------------- CSR build ----------------
__global__ __launch_bounds__(256) void scan_kernel(const int* __restrict__ cnt,
                                                   int* __restrict__ rowptr, int* __restrict__ cur) {
    __shared__ int part[256];
    int t = threadIdx.x;
    int base = t * 40;
    int local[40];
    int s = 0;
    #pragma unroll
    for (int i = 0; i < 40; i++) {
        int idx = base + i;
        int v = (idx < NN) ? cnt[idx] : 0;
        local[i] = s; s += v;
    }
    part[t] = s;
    __syncthreads();
    for (int off = 1; off < 256; off <<= 1) {
        int v = (t >= off) ? part[t - off] : 0;
        __syncthreads();
        part[t] += v;
        __syncthreads();
    }
    int pre = (t > 0) ? part[t - 1] : 0;
    #pragma unroll
    for (int i = 0; i < 40; i++) {
        int idx = base + i;
        if (idx < NN) { int r = pre + local[i]; rowptr[idx] = r; cur[idx] = r; }
    }
    if (t == 255) rowptr[NN] = part[255];
}

__global__ __launch_bounds__(256) void fill_kernel(const int* __restrict__ src,
                                                   int* __restrict__ cur, int* __restrict__ eidl) {
    int e = blockIdx.x * 256 + threadIdx.x;
    if (e < NE) {
        int slot = atomicAdd(&cur[src[e]], 1);
        eidl[slot] = e;
    }
}

// ---------------------------------------------------------------------------
// Edge kernel (MFMA), CSR-ordered:
//  - block processes eidl[e0..e0+16): edges grouped by source node, so the
//    block covers ~2-3 distinct nodes -> per-block LDS reduction + few
//    coalesced f32 atomics into out0. msg buffer + agg kernel eliminated.
//  - T1 B-fragments for it=0,1 prefetched into registers before T0 (hides
//    L2 latency behind staging).
//  - 5 barriers. LDS ~40 KB -> 4 blocks/CU.
// ---------------------------------------------------------------------------
__global__ __launch_bounds__(256, 4) void edge_mfma_kernel(
    const float* __restrict__ nf, const float* __restrict__ ef,
    const float* __restrict__ latg, const float* __restrict__ D1g, const float* __restrict__ D2g,
    const float* __restrict__ pb0, const int* __restrict__ srcg,
    const int* __restrict__ eidl, const __bf16* __restrict__ wsb, float* agg)
{
    __shared__ __align__(16) unsigned char pool[40064];
    __bf16* Cb   = (__bf16*)(pool + 0);       // [16][392]      T1 -> T4
    __bf16* aLat = (__bf16*)(pool + 12544);   // [4][64][8]     T0 -> T1
    __bf16* aSin = (__bf16*)(pool + 16640);   // [4][64][8]     T0 -> T1
    __bf16* v1m  = (__bf16*)(pool + 12544);   // [48][40]       T2 -> T3b (alias aLat)
    __bf16* v2m  = (__bf16*)(pool + 16384);   // [80][24]       T2 -> T3b (alias aSin)
    __bf16* mtile= (__bf16*)(pool + 12544);   // [16][248]      T4 -> T5  (alias aLat/aSin)
    __bf16* vt1  = (__bf16*)(pool + 20736);   // [16]x(stride 200): [3][64]  T0 -> T2
    __bf16* vt2  = (__bf16*)(pool + 27136);   // [16]x(stride 168): [5][32]  T0 -> T2
    __bf16* aV1g = (__bf16*)(pool + 20736);   // [3][64][8]     T3b -> T4 (alias vt1)
    __bf16* aV2g = (__bf16*)(pool + 23808);   // [5][64][8]     T3b -> T4 (alias vt1/vt2)
    float*  d1s  = (float*)(pool + 32512);    // [144]  raw D1  T0 -> T1
    float*  d2s  = (float*)(pool + 33088);    // [400]  raw D2  T0 -> T1
    float*  gts  = (float*)(pool + 32512);    // [16][49] f32   T2ph -> T3b (alias d1s/d2s)
    __bf16* aSact= (__bf16*)(pool + 35648);   // [2][64][8]     T2ph -> T4
    float*  e1s  = (float*)(pool + 37696);    // [144]  E1=D1·D1  T1 -> T3b
    float*  e2s  = (float*)(pool + 38272);    // [400]  E2=D2·D2  T1 -> T3b
    int*    srcs = (int*)  (pool + 39872);    // [16]  src node per row, T5 + planB
    int*    eids = (int*)  (pool + 39936);    // [16]  edge id per row (debug/unused later)

    const int t    = threadIdx.x;
    const int wid  = t >> 6, lane = t & 63;
    const int e0   = blockIdx.x * EB;

    #define EIDX(e) (eidl ? eidl[e0 + (e)] : (e0 + (e)))

    // ---- prefetch T1 B-frags for it=0,1 (independent of T0 staging) ----
    bf16x8 bpre[8];
    {
        const __bf16* b0 = wsb + OFF_WB1 + wid*2048;
        const __bf16* b1 = wsb + OFF_WB1 + (wid + 4)*2048;
        #pragma unroll
        for (int ks = 0; ks < 4; ks++) {
            bpre[ks]     = *(const bf16x8*)(b0 + (ks*64 + lane)*8);
            bpre[4 + ks] = *(const bf16x8*)(b1 + (ks*64 + lane)*8);
        }
    }

    if (t < 16) { int ee = EIDX(t); eids[t] = ee; srcs[t] = srcg[ee]; }

    // ---- T0: staging (threads read eidl/srcg directly; no barrier needed) ----
    for (int idx = t; idx < 144; idx += 256) {
        int e = idx / 9; int ee = EIDX(e);
        d1s[idx] = D1g[(size_t)ee*9 + (idx - e*9)];
    }
    for (int idx = t; idx < 400; idx += 256) {
        int e = idx / 25; int ee = EIDX(e);
        d2s[idx] = D2g[(size_t)ee*25 + (idx - e*25)];
    }
    {
        // vt1: 256 tasks, each = 12 consecutive floats (4 v1 channels), 3 bf16x4 writes
        int e = t >> 4, half = (t >> 3) & 1, cq = t & 7;
        int ee = EIDX(e);
        const float* base = half ? (ef + (size_t)ee*240 + 64 + cq*12)
                                 : (nf + (size_t)srcg[ee]*240 + 64 + cq*12);
        float4 f0 = *(const float4*)base;
        float4 f1 = *(const float4*)(base + 4);
        float4 f2 = *(const float4*)(base + 8);
        float f[12] = {f0.x,f0.y,f0.z,f0.w,f1.x,f1.y,f1.z,f1.w,f2.x,f2.y,f2.z,f2.w};
        int c = half*32 + cq*4;
        __bf16* dst = vt1 + e*200 + c;
        #pragma unroll
        for (int i = 0; i < 3; i++) {
            bf16x4 v = {(__bf16)f[i], (__bf16)f[3+i], (__bf16)f[6+i], (__bf16)f[9+i]};
            *(bf16x4*)(dst + i*64) = v;
        }
    }
    if (t < 128) {
        // vt2: 128 tasks, each = 20 consecutive floats (4 v2 channels), 5 bf16x4 writes
        int e = t >> 3, half = (t >> 2) & 1, cq = t & 3;
        int ee = EIDX(e);
        const float* base = half ? (ef + (size_t)ee*240 + 160 + cq*20)
                                 : (nf + (size_t)srcg[ee]*240 + 160 + cq*20);
        float f[20];
        #pragma unroll
        for (int k = 0; k < 5; k++) {
            float4 q4 = *(const float4*)(base + k*4);
            f[4*k] = q4.x; f[4*k+1] = q4.y; f[4*k+2] = q4.z; f[4*k+3] = q4.w;
        }
        int c = half*16 + cq*4;
        __bf16* dst = vt2 + e*168 + c;
        #pragma unroll
        for (int z = 0; z < 5; z++) {
            bf16x4 v = {(__bf16)f[z], (__bf16)f[5+z], (__bf16)f[10+z], (__bf16)f[15+z]};
            *(bf16x4*)(dst + z*32) = v;
        }
    }
    {
        int ks = t >> 6, l2 = t & 63, e = l2 & 15;
        int k0 = ks*32 + (l2 >> 4)*8;
        int ee = EIDX(e);
        {
            const float4* p4 = (const float4*)(latg + (size_t)ee*128 + k0);
            float4 f0 = p4[0], f1 = p4[1];
            bf16x8 v;
            v[0]=(__bf16)f0.x; v[1]=(__bf16)f0.y; v[2]=(__bf16)f0.z; v[3]=(__bf16)f0.w;
            v[4]=(__bf16)f1.x; v[5]=(__bf16)f1.y; v[6]=(__bf16)f1.z; v[7]=(__bf16)f1.w;
            *(bf16x8*)(aLat + t*8) = v;
        }
        {
            const float* s2 = (k0 < 64) ? (nf + (size_t)srcg[ee]*240 + k0)
                                        : (ef + (size_t)ee*240 + (k0 - 64));
            const float4* p4 = (const float4*)s2;
            float4 f0 = p4[0], f1 = p4[1];
            bf16x8 v;
            v[0]=(__bf16)f0.x; v[1]=(__bf16)f0.y; v[2]=(__bf16)f0.z; v[3]=(__bf16)f0.w;
            v[4]=(__bf16)f1.x; v[5]=(__bf16)f1.y; v[6]=(__bf16)f1.z; v[7]=(__bf16)f1.w;
            *(bf16x8*)(aSin + t*8) = v;
        }
    }
    __syncthreads();

    // ---- T1: GEMM1 + E = D·D matrices ----
    {
        int col16 = lane & 15, ebase = (lane >> 4)*4;
        bf16x8 aL[4], aS[4];
        #pragma unroll
        for (int ks = 0; ks < 4; ks++) {
            aL[ks] = *(const bf16x8*)(aLat + (ks*64 + lane)*8);
            aS[ks] = *(const bf16x8*)(aSin + (ks*64 + lane)*8);
        }
        #pragma unroll
        for (int it = 0; it < 6; it++) {
            int nt = wid + it*4;
            bool isLat = nt < 17;
            const __bf16* bB = isLat ? (wsb + OFF_WB1 + nt*2048)
                                     : (wsb + OFF_WB2 + (nt - 17)*2048);
            f32x4 acc = {0.f, 0.f, 0.f, 0.f};
            #pragma unroll
            for (int ks = 0; ks < 4; ks++) {
                bf16x8 b;
                if (it < 2) b = bpre[it*4 + ks];
                else        b = *(const bf16x8*)(bB + (ks*64 + lane)*8);
                acc = __builtin_amdgcn_mfma_f32_16x16x32_bf16(isLat ? aL[ks] : aS[ks], b, acc, 0, 0, 0);
            }
            int col = (isLat ? nt*16 : 272 + (nt - 17)*16) + col16;
            #pragma unroll
            for (int r = 0; r < 4; r++) Cb[(ebase + r)*392 + col] = (__bf16)acc[r];
        }
    }
    // E1[e][i][k] = sum_t D1[i][t] D1[t][k];  E2 likewise (5x5)
    for (int idx = t; idx < 544; idx += 256) {
        if (idx < 144) {
            int e = idx / 9, r = idx - e*9, i = r / 3, k = r - i*3;
            const float* d = d1s + e*9;
            e1s[idx] = d[i*3+0]*d[0*3+k] + d[i*3+1]*d[1*3+k] + d[i*3+2]*d[2*3+k];
        } else {
            int j = idx - 144;
            int e = j / 25, r = j - e*25, i = r / 5, k = r - i*5;
            const float* d = d2s + e*25;
            float a = 0.f;
            #pragma unroll
            for (int tt = 0; tt < 5; tt++) a += d[i*5+tt] * d[tt*5+k];
            e2s[j] = a;
        }
    }
    __syncthreads();

    // ---- T2: v GEMMs on UNROTATED inputs (A-frags = b128 reads from vt) ----
    {
        int col16 = lane & 15, er = lane & 15, q8 = (lane >> 4)*8, ebase = (lane >> 4)*4;
        for (int p = wid; p < 11; p += 4) {
            f32x4 acc = {0.f, 0.f, 0.f, 0.f};
            if (p < 6) {
                int i = p >> 1, nt = p & 1;
                #pragma unroll
                for (int ks = 0; ks < 2; ks++) {
                    bf16x8 a = *(const bf16x8*)(vt1 + er*200 + i*64 + ks*32 + q8);
                    bf16x8 b = *(const bf16x8*)(wsb + OFF_W1 + ((nt*2 + ks)*64 + lane)*8);
                    acc = __builtin_amdgcn_mfma_f32_16x16x32_bf16(a, b, acc, 0, 0, 0);
                }
                int col = nt*16 + col16;
                #pragma unroll
                for (int r = 0; r < 4; r++) v1m[(i*16 + ebase + r)*40 + col] = (__bf16)acc[r];
            } else {
                int i = p - 6;
                bf16x8 a = *(const bf16x8*)(vt2 + er*168 + i*32 + q8);
                bf16x8 b = *(const bf16x8*)(wsb + OFF_W2 + lane*8);
                acc = __builtin_amdgcn_mfma_f32_16x16x32_bf16(a, b, acc, 0, 0, 0);
                #pragma unroll
                for (int r = 0; r < 4; r++) v2m[(i*16 + ebase + r)*24 + col16] = (__bf16)acc[r];
            }
        }
    }
    // ---- T3a (same phase — independent of T2): s_act A-frag + gates ----
    if (t < 128) {
        int ks = t >> 6, l2 = t & 63, e = l2 & 15, o0 = ks*32 + (l2 >> 4)*8;
        bf16x8 v;
        #pragma unroll
        for (int j = 0; j < 8; j++) {
            int o = o0 + j;
            float x = (float)Cb[e*392 + 272 + o] * (float)Cb[e*392 + o];
            v[j] = (__bf16)(x * sigf(x));
        }
        *(bf16x8*)(aSact + t*8) = v;
    }
    for (int idx = t; idx < 768; idx += 256) {
        int e = idx / 48, o = idx - e*48;
        float x = (float)Cb[e*392 + 336 + o] * (float)Cb[e*392 + 64 + o];
        gts[e*49 + o] = sigf(x);
    }
    __syncthreads();

    // ---- T3b: single E-rotation + scale + gate -> A-frags (all b128 reads) ----
    for (int idx = t; idx < 512; idx += 256) {
        if (idx < 192) {
            int i = idx >> 6, l2 = idx & 63, e = l2 & 15, c0 = (l2 >> 4)*8;
            float z0 = e1s[e*9 + i*3], z1 = e1s[e*9 + i*3 + 1], z2 = e1s[e*9 + i*3 + 2];
            bf16x8 m0 = *(const bf16x8*)(v1m + (0*16 + e)*40 + c0);
            bf16x8 m1 = *(const bf16x8*)(v1m + (1*16 + e)*40 + c0);
            bf16x8 m2 = *(const bf16x8*)(v1m + (2*16 + e)*40 + c0);
            bf16x8 s8 = *(const bf16x8*)(Cb + e*392 + 112 + c0);
            bf16x8 v;
            #pragma unroll
            for (int j = 0; j < 8; j++) {
                float g = gts[e*49 + c0 + j];
                float a = z0*(float)m0[j] + z1*(float)m1[j] + z2*(float)m2[j];
                v[j] = (__bf16)(g * (float)s8[j] * a);
            }
            *(bf16x8*)(aV1g + idx*8) = v;
        } else {
            int idx2 = idx - 192;
            int i = idx2 >> 6, l2 = idx2 & 63, e = l2 & 15, c0 = (l2 >> 4)*8;
            bf16x8 v;
            if (c0 < 16) {
                const float* ee = e2s + e*25 + i*5;
                float z0 = ee[0], z1 = ee[1], z2 = ee[2], z3 = ee[3], z4 = ee[4];
                bf16x8 m0 = *(const bf16x8*)(v2m + (0*16 + e)*24 + c0);
                bf16x8 m1 = *(const bf16x8*)(v2m + (1*16 + e)*24 + c0);
                bf16x8 m2 = *(const bf16x8*)(v2m + (2*16 + e)*24 + c0);
                bf16x8 m3 = *(const bf16x8*)(v2m + (3*16 + e)*24 + c0);
                bf16x8 m4 = *(const bf16x8*)(v2m + (4*16 + e)*24 + c0);
                bf16x8 s8 = *(const bf16x8*)(Cb + e*392 + 144 + c0);
                #pragma unroll
                for (int j = 0; j < 8; j++) {
                    float g = gts[e*49 + 32 + c0 + j];
                    float a = z0*(float)m0[j] + z1*(float)m1[j] + z2*(float)m2[j]
                            + z3*(float)m3[j] + z4*(float)m4[j];
                    v[j] = (__bf16)(g * (float)s8[j] * a);
                }
            } else {
                #pragma unroll
                for (int j = 0; j < 8; j++) v[j] = (__bf16)0.0f;
            }
            *(bf16x8*)(aV2g + idx2*8) = v;
        }
    }
    __syncthreads();

    // ---- T4: post GEMMs, env scale -> LDS message tile (or atomic fallback) ----
    {
        int col16 = lane & 15, ebase = (lane >> 4)*4;
        for (int p = wid; p < 15; p += 4) {
            f32x4 acc = {0.f, 0.f, 0.f, 0.f};
            if (p < 4) {
                int nt = p;
                #pragma unroll
                for (int ks = 0; ks < 2; ks++) {
                    bf16x8 a = *(const bf16x8*)(aSact + (ks*64 + lane)*8);
                    bf16x8 b = *(const bf16x8*)(wsb + OFF_PW0 + ((nt*2 + ks)*64 + lane)*8);
                    acc = __builtin_amdgcn_mfma_f32_16x16x32_bf16(a, b, acc, 0, 0, 0);
                }
                int o = nt*16 + col16;
                float bias = pb0[o];
                #pragma unroll
                for (int r = 0; r < 4; r++) {
                    int e = ebase + r;
                    float val = (acc[r] + bias) * (float)Cb[e*392 + 160 + o];
                    if (eidl) mtile[e*248 + o] = (__bf16)val;
                    else      atomicAdd(agg + (size_t)srcs[e]*240 + o, val);
                }
            } else if (p < 10) {
                int q = p - 4, i = q >> 1, nt = q & 1;
                bf16x8 a = *(const bf16x8*)(aV1g + (i*64 + lane)*8);
                bf16x8 b = *(const bf16x8*)(wsb + OFF_PW1 + (nt*64 + lane)*8);
                acc = __builtin_amdgcn_mfma_f32_16x16x32_bf16(a, b, acc, 0, 0, 0);
                int o = nt*16 + col16;
                #pragma unroll
                for (int r = 0; r < 4; r++) {
                    int e = ebase + r;
                    float val = acc[r] * (float)Cb[e*392 + 224 + o];
                    if (eidl) mtile[e*248 + 64 + o*3 + i] = (__bf16)val;
                    else      atomicAdd(agg + (size_t)srcs[e]*240 + 64 + o*3 + i, val);
                }
            } else {
                int i = p - 10;
                bf16x8 a = *(const bf16x8*)(aV2g + (i*64 + lane)*8);
                bf16x8 b = *(const bf16x8*)(wsb + OFF_PW2 + lane*8);
                acc = __builtin_amdgcn_mfma_f32_16x16x32_bf16(a, b, acc, 0, 0, 0);
                #pragma unroll
                for (int r = 0; r < 4; r++) {
                    int e = ebase + r;
                    float val = acc[r] * (float)Cb[e*392 + 256 + col16];
                    if (eidl) mtile[e*248 + 160 + col16*5 + i] = (__bf16)val;
                    else      atomicAdd(agg + (size_t)srcs[e]*240 + 160 + col16*5 + i, val);
                }
            }
        }
    }

    // ---- T5: segmented reduction over the 16 rows -> few coalesced atomics ----
    if (eidl) {
        __syncthreads();
        if (t < 240) {
            float s = 0.f;
            int prev = srcs[0];
            #pragma unroll
            for (int e = 0; e < EB; e++) {
                int sn = srcs[e];           // wave-uniform
                if (sn != prev) {
                    atomicAdd(agg + (size_t)prev*240 + t, s);
                    s = 0.f; prev = sn;
                }
                s += (float)mtile[e*248 + t];
            }
            atomicAdd(agg + (size_t)prev*240 + t, s);
        }
    }
    #undef EIDX
}

// ---------------------------------------------------------------------------
// Node kernel (unchanged)
// ---------------------------------------------------------------------------
__global__ __launch_bounds__(256, 2) void node_kernel(
    const float* __restrict__ nf, const float* __restrict__ mcplg,
    const float* __restrict__ ohg,
    const float* __restrict__ cW1, const float* __restrict__ cb1,
    const float* __restrict__ cW2, const float* __restrict__ cb2,
    const float* __restrict__ gsW, const float* __restrict__ gsb,
    const float* __restrict__ mW1, const float* __restrict__ mb1,
    const float* __restrict__ mW2, const float* __restrict__ mb2,
    const float* __restrict__ lng, const float* __restrict__ lnb,
    const float* __restrict__ rW0, const float* __restrict__ rb0,
    const float* __restrict__ rW1, const float* __restrict__ rW2,
    const float* __restrict__ ohT, float* out0, float* out1)
{
    __shared__ __align__(16) unsigned char pool[68608];
    float* mcp  = (float*)(pool + 0);      // [16][128]
    float* ohv  = (float*)(pool + 8192);   // [16][96]
    float* nsr  = (float*)(pool + 14336);  // [16][240]
    float* anew = (float*)(pool + 29696);  // [16][240]
    float* t12  = (float*)(pool + 45056);  // [16][128]
    float* cfg  = (float*)(pool + 53248);  // [16][112]
    float* scm  = (float*)(pool + 60416);  // [16][128]

    const int t  = threadIdx.x;
    const int g  = t >> 7;
    const int o  = t & 127;
    const int nb = g * 8;
    const int n0 = blockIdx.x * NPB;

    for (int idx = t; idx < NPB * 128; idx += 256) {
        int n = idx >> 7, k = idx & 127;
        mcp[n*128 + k] = mcplg[(n0 + n) * 128 + k];
    }
    for (int idx = t; idx < NPB * 96; idx += 256) {
        int n = idx / 96, k = idx - n * 96;
        ohv[n*96 + k] = (k < 95) ? ohg[(n0 + n) * 95 + k] : 0.f;
    }
    for (int idx = t; idx < NPB * 240; idx += 256) {
        int n = idx / 240, k = idx - n * 240;
        nsr[n*240 + k]  = nf[(n0 + n) * DIM + k];
        anew[n*240 + k] = out0[(n0 + n) * DIM + k];
    }
    __syncthreads();

    {
        float a[8]; float b = cb1[o];
        #pragma unroll
        for (int i = 0; i < 8; i++) a[i] = b;
        #pragma unroll 2
        for (int k4 = 0; k4 < 32; k4++) {
            float w0 = cW1[(4*k4+0)*128 + o], w1 = cW1[(4*k4+1)*128 + o],
                  w2 = cW1[(4*k4+2)*128 + o], w3 = cW1[(4*k4+3)*128 + o];
            #pragma unroll
            for (int i = 0; i < 8; i++) {
                float4 m = *(const float4*)&mcp[(nb+i)*128 + 4*k4];
                a[i] += m.x*w0 + m.y*w1 + m.z*w2 + m.w*w3;
            }
        }
        #pragma unroll
        for (int i = 0; i < 8; i++) { float x = a[i]; t12[(nb+i)*128 + o] = x * sigf(x); }
    }
    __syncthreads();

    if (o < 112) {
        float a[8]; float b = cb2[o];
        #pragma unroll
        for (int i = 0; i < 8; i++) a[i] = b;
        #pragma unroll 2
        for (int k4 = 0; k4 < 32; k4++) {
            float w0 = cW2[(4*k4+0)*112 + o], w1 = cW2[(4*k4+1)*112 + o],
                  w2 = cW2[(4*k4+2)*112 + o], w3 = cW2[(4*k4+3)*112 + o];
            #pragma unroll
            for (int i = 0; i < 8; i++) {
                float4 m = *(const float4*)&t12[(nb+i)*128 + 4*k4];
                a[i] += m.x*w0 + m.y*w1 + m.z*w2 + m.w*w3;
            }
        }
        #pragma unroll
        for (int i = 0; i < 8; i++) cfg[(nb+i)*112 + o] = a[i];
    }
    __syncthreads();

    for (int idx = t; idx < NPB * 240; idx += 256) {
        int n = idx / 240, d = idx - n * 240;
        int ch = (d < 64) ? d : (d < 160 ? 64 + (d - 64) / 3 : 96 + (d - 160) / 5);
        anew[n*240 + d] *= 0.25f * cfg[n*112 + ch];
    }
    __syncthreads();

    {
        float a[8]; float b = gsb[o];
        #pragma unroll
        for (int i = 0; i < 8; i++) a[i] = b;
        #pragma unroll 2
        for (int k4 = 0; k4 < 16; k4++) {
            float w0 = gsW[(4*k4+0)*128 + o], w1 = gsW[(4*k4+1)*128 + o],
                  w2 = gsW[(4*k4+2)*128 + o], w3 = gsW[(4*k4+3)*128 + o];
            #pragma unroll
            for (int i = 0; i < 8; i++) {
                float4 m = *(const float4*)&anew[(nb+i)*240 + 4*k4];
                a[i] += m.x*w0 + m.y*w1 + m.z*w2 + m.w*w3;
            }
        }
        #pragma unroll
        for (int i = 0; i < 8; i++) scm[(nb+i)*128 + o] = a[i];
    }
    __syncthreads();

    {
        float a[8]; float b = mb1[o];
        #pragma unroll
        for (int i = 0; i < 8; i++) a[i] = b;
        #pragma unroll 2
        for (int k4 = 0; k4 < 32; k4++) {
            float w0 = mW1[(4*k4+0)*128 + o], w1 = mW1[(4*k4+1)*128 + o],
                  w2 = mW1[(4*k4+2)*128 + o], w3 = mW1[(4*k4+3)*128 + o];
            #pragma unroll
            for (int i = 0; i < 8; i++) {
                float4 m = *(const float4*)&scm[(nb+i)*128 + 4*k4];
                a[i] += m.x*w0 + m.y*w1 + m.z*w2 + m.w*w3;
            }
        }
        #pragma unroll 2
        for (int k4 = 0; k4 < 32; k4++) {
            float w0 = mW1[(128+4*k4+0)*128 + o], w1 = mW1[(128+4*k4+1)*128 + o],
                  w2 = mW1[(128+4*k4+2)*128 + o], w3 = mW1[(128+4*k4+3)*128 + o];
            #pragma unroll
            for (int i = 0; i < 8; i++) {
                float4 m = *(const float4*)&mcp[(nb+i)*128 + 4*k4];
                a[i] += m.x*w0 + m.y*w1 + m.z*w2 + m.w*w3;
            }
        }
        #pragma unroll
        for (int i = 0; i < 8; i++) { float x = a[i]; t12[(nb+i)*128 + o] = x * sigf(x); }
    }
    __syncthreads();

    {
        float a[8]; float b = mb2[o];
        #pragma unroll
        for (int i = 0; i < 8; i++) a[i] = b;
        #pragma unroll 2
        for (int k4 = 0; k4 < 32; k4++) {
            float w0 = mW2[(4*k4+0)*128 + o], w1 = mW2[(4*k4+1)*128 + o],
                  w2 = mW2[(4*k4+2)*128 + o], w3 = mW2[(4*k4+3)*128 + o];
            #pragma unroll
            for (int i = 0; i < 8; i++) {
                float4 m = *(const float4*)&t12[(nb+i)*128 + 4*k4];
                a[i] += m.x*w0 + m.y*w1 + m.z*w2 + m.w*w3;
            }
        }
        #pragma unroll
        for (int i = 0; i < 8; i++) scm[(nb+i)*128 + o] = mcp[(nb+i)*128 + o] + a[i];
    }
    __syncthreads();

    {
        int n = t >> 4, l = t & 15;
        float x[8]; float s = 0.f, ss = 0.f;
        #pragma unroll
        for (int i = 0; i < 8; i++) { x[i] = scm[n*128 + l + 16*i]; s += x[i]; ss += x[i]*x[i]; }
        #pragma unroll
        for (int off = 8; off > 0; off >>= 1) {
            s  += __shfl_down(s,  off, 16);
            ss += __shfl_down(ss, off, 16);
        }
        s  = __shfl(s, 0, 16);
        ss = __shfl(ss, 0, 16);
        float mu   = s * (1.f / 128.f);
        float var  = ss * (1.f / 128.f) - mu * mu;
        float rstd = rsqrtf(var + 1e-5f);
        float* op = out1 + (n0 + n) * 128;
        #pragma unroll
        for (int i = 0; i < 8; i++) {
            int c = l + 16*i;
            op[c] = (x[i] - mu) * rstd * lng[c] + lnb[c];
        }
    }

    if (o < 112) {
        float a[8] = {0.f,0.f,0.f,0.f,0.f,0.f,0.f,0.f};
        #pragma unroll 2
        for (int k4 = 0; k4 < 24; k4++) {
            float w0 = ohT[(4*k4+0)*112 + o], w1 = ohT[(4*k4+1)*112 + o],
                  w2 = ohT[(4*k4+2)*112 + o], w3 = ohT[(4*k4+3)*112 + o];
            #pragma unroll
            for (int i = 0; i < 8; i++) {
                float4 m = *(const float4*)&ohv[(nb+i)*96 + 4*k4];
                a[i] += m.x*w0 + m.y*w1 + m.z*w2 + m.w*w3;
            }
        }
        #pragma unroll
        for (int i = 0; i < 8; i++) cfg[(nb+i)*112 + o] = a[i];
    }
    __syncthreads();

    const float c_new = 0.4472135955f;
    const float c_old = 0.8944271910f;
    for (int idx = t; idx < NPB * 240; idx += 256) {
        int n = idx / 240, d = idx - n * 240;
        float res, gg;
        if (d < 64) {
            float acc = rb0[d];
            #pragma unroll 4
            for (int c = 0; c < 64; c++) acc += nsr[n*240 + c] * rW0[c * 64 + d];
            res = acc; gg = cfg[n*112 + d];
        } else if (d < 160) {
            int dd = d - 64, oo = dd / 3, j = dd - oo * 3;
            float acc = 0.f;
            #pragma unroll 4
            for (int c = 0; c < 32; c++) acc += nsr[n*240 + 64 + c*3 + j] * rW1[c * 32 + oo];
            res = acc; gg = cfg[n*112 + 64 + oo];
        } else {
            int dd = d - 160, oo = dd / 5, j = dd - oo * 5;
            float acc = 0.f;
            #pragma unroll 4
            for (int c = 0; c < 16; c++) acc += nsr[n*240 + 160 + c*5 + j] * rW2[c * 16 + oo];
            res = acc; gg = cfg[n*112 + 96 + oo];
        }
        float v = c_new * anew[n*240 + d] + c_old * res;
        out0[(n0 + n) * DIM + d] = v * (1.f + gg);
    }
}

extern "C" void kernel_launch(void* const* d_in, const int* in_sizes, int n_in,
                              void* d_out, int out_size, void* d_ws, size_t ws_size,
                              hipStream_t stream) {
    const float* nf      = (const float*)d_in[0];
    const float* ef      = (const float*)d_in[1];
    const float* lat     = (const float*)d_in[2];
    const float* mcpl    = (const float*)d_in[3];
    const float* ohot    = (const float*)d_in[4];
    const float* D1      = (const float*)d_in[5];
    const float* D2      = (const float*)d_in[6];
    const float* so2_W0  = (const float*)d_in[7];
    const float* so2_W1  = (const float*)d_in[8];
    const float* so2_W2  = (const float*)d_in[9];
    const float* so2_Ws  = (const float*)d_in[10];
    const float* env_W   = (const float*)d_in[11];
    const float* post_W0 = (const float*)d_in[12];
    const float* post_b0 = (const float*)d_in[13];
    const float* post_W1 = (const float*)d_in[14];
    const float* post_W2 = (const float*)d_in[15];
    const float* res_W0  = (const float*)d_in[16];
    const float* res_b0  = (const float*)d_in[17];
    const float* res_W1  = (const float*)d_in[18];
    const float* res_W2  = (const float*)d_in[19];
    const float* cpl_W1  = (const float*)d_in[20];
    const float* cpl_b1  = (const float*)d_in[21];
    const float* cpl_W2  = (const float*)d_in[22];
    const float* cpl_b2  = (const float*)d_in[23];
    const float* gs_W    = (const float*)d_in[24];
    const float* gs_b    = (const float*)d_in[25];
    const float* msg_W1  = (const float*)d_in[26];
    const float* msg_b1  = (const float*)d_in[27];
    const float* msg_W2  = (const float*)d_in[28];
    const float* msg_b2  = (const float*)d_in[29];
    const float* ln_g    = (const float*)d_in[30];
    const float* ln_b    = (const float*)d_in[31];
    const float* oh_w0   = (const float*)d_in[32];
    const float* oh_w1   = (const float*)d_in[33];
    const float* oh_w2   = (const float*)d_in[34];
    const int*   eidx    = (const int*)d_in[35];   // (2,E); row 0 = src

    float* out0 = (float*)d_out;                     // N*DIM, doubles as agg
    float* out1 = (float*)d_out + (size_t)NN * DIM;  // N*CPL
    char*   wsB = (char*)d_ws;
    __bf16* wsb = (__bf16*)d_ws;
    float*  ohT = (float*)(wsB + OHT_BYTE_OFF);

    const size_t needA = (size_t)EID_BYTE_OFF + (size_t)NE * sizeof(int);
    const bool planA = ws_size >= needA;

    (void)hipMemsetAsync(out0, 0, (size_t)NN * DIM * sizeof(float), stream);

    if (planA) {
        int* cnt  = (int*)(wsB + CNT_BYTE_OFF);
        int* row  = (int*)(wsB + ROW_BYTE_OFF);
        int* cur  = (int*)(wsB + CUR_BYTE_OFF);
        int* eidl = (int*)(wsB + EID_BYTE_OFF);

        (void)hipMemsetAsync(cnt, 0, 10240 * sizeof(int), stream);
        prep_kernel<<<56 + (NE + 255) / 256, 256, 0, stream>>>(
            so2_Ws, env_W, so2_W0, so2_W1, so2_W2, post_W0, post_W1, post_W2,
            oh_w0, oh_w1, oh_w2, wsb, ohT, eidx, cnt);
        scan_kernel<<<1, 256, 0, stream>>>(cnt, row, cur);
        fill_kernel<<<(NE + 255) / 256, 256, 0, stream>>>(eidx, cur, eidl);

        edge_mfma_kernel<<<NE / EB, 256, 0, stream>>>(
            nf, ef, lat, D1, D2, post_b0, eidx, eidl, wsb, out0);
    } else {
        prep_kernel<<<56, 256, 0, stream>>>(
            so2_Ws, env_W, so2_W0, so2_W1, so2_W2, post_W0, post_W1, post_W2,
            oh_w0, oh_w1, oh_w2, wsb, ohT, eidx, nullptr);
        edge_mfma_kernel<<<NE / EB, 256, 0, stream>>>(
            nf, ef, lat, D1, D2, post_b0, eidx, nullptr, wsb, out0);
    }

    node_kernel<<<NN / NPB, 256, 0, stream>>>(
        nf, mcpl, ohot, cpl_W1, cpl_b1, cpl_W2, cpl_b2, gs_W, gs_b,
        msg_W1, msg_b1, msg_W2, msg_b2, ln_g, ln_b,
        res_W0, res_b0, res_W1, res_W2, ohT, out0, out1);
}

// Round 3
// 689.210 us; speedup vs baseline: 1.0876x; 1.0089x over previous
//
#include <hip/hip_runtime.h>

#define NN   10000
#define NE   160000
#define DIM  240
#define EB   16    // edges per block (edge kernel)
#define NPB  16    // nodes per block (node kernel)

typedef __bf16 bf16x8 __attribute__((ext_vector_type(8)));
typedef __bf16 bf16x4 __attribute__((ext_vector_type(4)));
typedef float  f32x4  __attribute__((ext_vector_type(4)));

__device__ __forceinline__ float sigf(float x) { return 1.0f / (1.0f + __expf(-x)); }

// -------- workspace layout --------
#define OFF_WB1 0        // [Ws|We]: N=272 (17 nt), K=128 (4 ks)
#define OFF_WB2 34816    // W0:      N=112 (7 nt),  K=128 (4 ks)
#define OFF_W1  49152    // so2_W1:  N=32 (2 nt),   K=64  (2 ks)
#define OFF_W2  51200    // so2_W2:  N=16 (1 nt),   K=32  (1 ks)
#define OFF_PW0 51712    // post_W0: N=64 (4 nt),   K=64  (2 ks)
#define OFF_PW1 55808    // post_W1: N=32 (2 nt),   K=32  (1 ks)
#define OFF_PW2 56832    // post_W2: N=16 (1 nt),   K=16 pad 32
#define OHT_BYTE_OFF 131072     // float [96][112]
#define CNT_BYTE_OFF 196608     // int [10240]
#define ROW_BYTE_OFF 237568     // int [10016]
#define CUR_BYTE_OFF 282624     // int [10240]
#define EID_BYTE_OFF 327680     // int [160000]

__global__ __launch_bounds__(256) void prep_kernel(
    const float* __restrict__ Ws, const float* __restrict__ We, const float* __restrict__ W0,
    const float* __restrict__ W1, const float* __restrict__ W2,
    const float* __restrict__ pW0, const float* __restrict__ pW1, const float* __restrict__ pW2,
    const float* __restrict__ w0g, const float* __restrict__ w1g, const float* __restrict__ w2g,
    __bf16* __restrict__ wsb, float* __restrict__ ohT,
    const int* __restrict__ src, int* __restrict__ cnt)
{
    if (blockIdx.x >= 56) {
        if (cnt) {
            int e = (blockIdx.x - 56) * 256 + threadIdx.x;
            if (e < NE) atomicAdd(&cnt[src[e]], 1);
        }
        return;
    }
    int tid = blockIdx.x * 256 + threadIdx.x;
    const int stride = 56 * 256;
    for (int idx = tid; idx < 17*4*512; idx += stride) {
        int j = idx & 7, lane = (idx >> 3) & 63, ks = (idx >> 9) & 3, nt = idx >> 11;
        int k = ks*32 + (lane >> 4)*8 + j, n = nt*16 + (lane & 15);
        float v = (n < 160) ? Ws[k*160 + n] : We[k*112 + (n - 160)];
        wsb[OFF_WB1 + idx] = (__bf16)v;
    }
    for (int idx = tid; idx < 7*4*512; idx += stride) {
        int j = idx & 7, lane = (idx >> 3) & 63, ks = (idx >> 9) & 3, nt = idx >> 11;
        int k = ks*32 + (lane >> 4)*8 + j, n = nt*16 + (lane & 15);
        wsb[OFF_WB2 + idx] = (__bf16)W0[k*112 + n];
    }
    for (int idx = tid; idx < 2*2*512; idx += stride) {
        int j = idx & 7, lane = (idx >> 3) & 63, ks = (idx >> 9) & 1, nt = idx >> 10;
        int k = ks*32 + (lane >> 4)*8 + j, n = nt*16 + (lane & 15);
        wsb[OFF_W1 + idx] = (__bf16)W1[k*32 + n];
    }
    for (int idx = tid; idx < 512; idx += stride) {
        int j = idx & 7, lane = (idx >> 3) & 63;
        int k = (lane >> 4)*8 + j, n = lane & 15;
        wsb[OFF_W2 + idx] = (__bf16)W2[k*16 + n];
    }
    for (int idx = tid; idx < 4*2*512; idx += stride) {
        int j = idx & 7, lane = (idx >> 3) & 63, ks = (idx >> 9) & 1, nt = idx >> 10;
        int k = ks*32 + (lane >> 4)*8 + j, n = nt*16 + (lane & 15);
        wsb[OFF_PW0 + idx] = (__bf16)pW0[k*64 + n];
    }
    for (int idx = tid; idx < 2*512; idx += stride) {
        int j = idx & 7, lane = (idx >> 3) & 63, nt = idx >> 9;
        int k = (lane >> 4)*8 + j, n = nt*16 + (lane & 15);
        wsb[OFF_PW1 + idx] = (__bf16)pW1[k*32 + n];
    }
    for (int idx = tid; idx < 512; idx += stride) {
        int j = idx & 7, lane = (idx >> 3) & 63;
        int k = (lane >> 4)*8 + j, n = lane & 15;
        wsb[OFF_PW2 + idx] = (k < 16) ? (__bf16)pW2[k*16 + n] : (__bf16)0.0f;
    }
    for (int idx = tid; idx < 96*112; idx += stride) {
        int k = idx / 112, n2 = idx - k*112;
        float v = 0.f;
        if (k < 95) {
            if (n2 < 64)      v = w0g[n2*95 + k];
            else if (n2 < 96) v = w1g[(n2-64)*95 + k];
            else              v = w2g[(n2-96)*95 + k];
        }
        ohT[idx] = v * 0.10259783521f;
    }
}

// ---------------- CSR build ----------------
__global__ __launch_bounds__(256) void scan_kernel(const int* __restrict__ cnt,
                                                   int* __restrict__ rowptr, int* __restrict__ cur) {
    __shared__ int part[256];
    int t = threadIdx.x;
    int base = t * 40;
    int local[40];
    int s = 0;
    #pragma unroll
    for (int i = 0; i < 40; i++) {
        int idx = base + i;
        int v = (idx < NN) ? cnt[idx] : 0;
        local[i] = s; s += v;
    }
    part[t] = s;
    __syncthreads();
    for (int off = 1; off < 256; off <<= 1) {
        int v = (t >= off) ? part[t - off] : 0;
        __syncthreads();
        part[t] += v;
        __syncthreads();
    }
    int pre = (t > 0) ? part[t - 1] : 0;
    #pragma unroll
    for (int i = 0; i < 40; i++) {
        int idx = base + i;
        if (idx < NN) { int r = pre + local[i]; rowptr[idx] = r; cur[idx] = r; }
    }
    if (t == 255) rowptr[NN] = part[255];
}

__global__ __launch_bounds__(256) void fill_kernel(const int* __restrict__ src,
                                                   int* __restrict__ cur, int* __restrict__ eidl) {
    int e = blockIdx.x * 256 + threadIdx.x;
    if (e < NE) {
        int slot = atomicAdd(&cur[src[e]], 1);
        eidl[slot] = e;
    }
}

// ---------------------------------------------------------------------------
// Edge kernel (MFMA), CSR-ordered, async-decoupled:
//  P0: stage vt1/vt2/d to LDS (+srcs).            (no barrier)
//  P1: GEMM1 with A-frags loaded DIRECT from global (no LDS round-trip),
//      hides P0 latency under MFMA.  barrier.
//  P2: v-GEMMs + s_act frag + E=D·D.              barrier.
//  P3: E-rotation + scale + inline gates -> A-frags. barrier.
//  P4: post GEMMs -> mtile.                        barrier.
//  P5: segmented reduction -> few coalesced atomics.
//  4+1 barriers, LDS 39936 -> 4 blocks/CU.
// ---------------------------------------------------------------------------
__global__ __launch_bounds__(256, 4) void edge_mfma_kernel(
    const float* __restrict__ nf, const float* __restrict__ ef,
    const float* __restrict__ latg, const float* __restrict__ D1g, const float* __restrict__ D2g,
    const float* __restrict__ pb0, const int* __restrict__ srcg,
    const int* __restrict__ eidl, const __bf16* __restrict__ wsb, float* agg)
{
    __shared__ __align__(16) unsigned char pool[39936];
    __bf16* Cb   = (__bf16*)(pool + 0);       // [16][392]      P1 -> P4
    __bf16* v1m  = (__bf16*)(pool + 12544);   // [48][40]       P2 -> P3
    __bf16* v2m  = (__bf16*)(pool + 16384);   // [80][24]       P2 -> P3
    __bf16* mtile= (__bf16*)(pool + 12544);   // [16][248]      P4 -> P5 (alias v1m/v2m)
    __bf16* vt1  = (__bf16*)(pool + 20736);   // [16]x stride200: [3][64]  P0 -> P2
    __bf16* vt2  = (__bf16*)(pool + 27136);   // [16]x stride168: [5][32]  P0 -> P2
    __bf16* aV1g = (__bf16*)(pool + 20736);   // [3][64][8]     P3 -> P4 (alias vt1)
    __bf16* aV2g = (__bf16*)(pool + 23808);   // [5][64][8]     P3 -> P4 (alias vt1/vt2)
    float*  d1s  = (float*)(pool + 32512);    // [144]  raw D1  P0 -> P2
    float*  d2s  = (float*)(pool + 33088);    // [400]  raw D2  P0 -> P2
    __bf16* aSact= (__bf16*)(pool + 35648);   // [2][64][8]     P2 -> P4
    float*  e1s  = (float*)(pool + 37696);    // [144]  E1=D1·D1  P2 -> P3
    float*  e2s  = (float*)(pool + 38272);    // [400]  E2=D2·D2  P2 -> P3
    int*    srcs = (int*)  (pool + 39872);    // [16]

    const int t    = threadIdx.x;
    const int wid  = t >> 6, lane = t & 63;
    const int e0   = blockIdx.x * EB;

    #define EIDX(e) (eidl ? eidl[e0 + (e)] : (e0 + (e)))

    if (t < 16) srcs[t] = srcg[EIDX(t)];

    // ---- P0: staging to LDS ----
    for (int idx = t; idx < 144; idx += 256) {
        int e = idx / 9; int ee = EIDX(e);
        d1s[idx] = D1g[(size_t)ee*9 + (idx - e*9)];
    }
    for (int idx = t; idx < 400; idx += 256) {
        int e = idx / 25; int ee = EIDX(e);
        d2s[idx] = D2g[(size_t)ee*25 + (idx - e*25)];
    }
    {
        int e = t >> 4, half = (t >> 3) & 1, cq = t & 7;
        int ee = EIDX(e);
        const float* base = half ? (ef + (size_t)ee*240 + 64 + cq*12)
                                 : (nf + (size_t)srcg[ee]*240 + 64 + cq*12);
        float4 f0 = *(const float4*)base;
        float4 f1 = *(const float4*)(base + 4);
        float4 f2 = *(const float4*)(base + 8);
        float f[12] = {f0.x,f0.y,f0.z,f0.w,f1.x,f1.y,f1.z,f1.w,f2.x,f2.y,f2.z,f2.w};
        int c = half*32 + cq*4;
        __bf16* dst = vt1 + e*200 + c;
        #pragma unroll
        for (int i = 0; i < 3; i++) {
            bf16x4 v = {(__bf16)f[i], (__bf16)f[3+i], (__bf16)f[6+i], (__bf16)f[9+i]};
            *(bf16x4*)(dst + i*64) = v;
        }
    }
    if (t < 128) {
        int e = t >> 3, half = (t >> 2) & 1, cq = t & 3;
        int ee = EIDX(e);
        const float* base = half ? (ef + (size_t)ee*240 + 160 + cq*20)
                                 : (nf + (size_t)srcg[ee]*240 + 160 + cq*20);
        float f[20];
        #pragma unroll
        for (int k = 0; k < 5; k++) {
            float4 q4 = *(const float4*)(base + k*4);
            f[4*k] = q4.x; f[4*k+1] = q4.y; f[4*k+2] = q4.z; f[4*k+3] = q4.w;
        }
        int c = half*16 + cq*4;
        __bf16* dst = vt2 + e*168 + c;
        #pragma unroll
        for (int z = 0; z < 5; z++) {
            bf16x4 v = {(__bf16)f[z], (__bf16)f[5+z], (__bf16)f[10+z], (__bf16)f[15+z]};
            *(bf16x4*)(dst + z*32) = v;
        }
    }

    // ---- P1: GEMM1, A-fragments direct from global (no barrier needed) ----
    {
        int col16 = lane & 15, ebase = (lane >> 4)*4;
        int e = lane & 15, q = lane >> 4;
        int ee = EIDX(e); int sn = srcg[ee];
        const float* latp = latg + (size_t)ee*128 + q*8;
        const float* nfp  = nf  + (size_t)sn*240 + q*8;
        const float* efp  = ef  + (size_t)ee*240 + q*8;
        bf16x8 aL[4], aS[4];
        #pragma unroll
        for (int ks = 0; ks < 4; ks++) {
            float4 f0 = *(const float4*)(latp + ks*32);
            float4 f1 = *(const float4*)(latp + ks*32 + 4);
            bf16x8 v;
            v[0]=(__bf16)f0.x; v[1]=(__bf16)f0.y; v[2]=(__bf16)f0.z; v[3]=(__bf16)f0.w;
            v[4]=(__bf16)f1.x; v[5]=(__bf16)f1.y; v[6]=(__bf16)f1.z; v[7]=(__bf16)f1.w;
            aL[ks] = v;
            const float* sp = (ks < 2) ? (nfp + ks*32) : (efp + (ks - 2)*32);
            float4 g0 = *(const float4*)sp;
            float4 g1 = *(const float4*)(sp + 4);
            bf16x8 w;
            w[0]=(__bf16)g0.x; w[1]=(__bf16)g0.y; w[2]=(__bf16)g0.z; w[3]=(__bf16)g0.w;
            w[4]=(__bf16)g1.x; w[5]=(__bf16)g1.y; w[6]=(__bf16)g1.z; w[7]=(__bf16)g1.w;
            aS[ks] = w;
        }
        #pragma unroll
        for (int it = 0; it < 6; it++) {
            int nt = wid + it*4;
            bool isLat = nt < 17;
            const __bf16* bB = isLat ? (wsb + OFF_WB1 + nt*2048)
                                     : (wsb + OFF_WB2 + (nt - 17)*2048);
            f32x4 acc = {0.f, 0.f, 0.f, 0.f};
            #pragma unroll
            for (int ks = 0; ks < 4; ks++) {
                bf16x8 b = *(const bf16x8*)(bB + (ks*64 + lane)*8);
                acc = __builtin_amdgcn_mfma_f32_16x16x32_bf16(isLat ? aL[ks] : aS[ks], b, acc, 0, 0, 0);
            }
            int col = (isLat ? nt*16 : 272 + (nt - 17)*16) + col16;
            #pragma unroll
            for (int r = 0; r < 4; r++) Cb[(ebase + r)*392 + col] = (__bf16)acc[r];
        }
    }
    __syncthreads();

    // ---- P2: v GEMMs + s_act frag + E = D·D ----
    {
        int col16 = lane & 15, er = lane & 15, q8 = (lane >> 4)*8, ebase = (lane >> 4)*4;
        for (int p = wid; p < 11; p += 4) {
            f32x4 acc = {0.f, 0.f, 0.f, 0.f};
            if (p < 6) {
                int i = p >> 1, nt = p & 1;
                #pragma unroll
                for (int ks = 0; ks < 2; ks++) {
                    bf16x8 a = *(const bf16x8*)(vt1 + er*200 + i*64 + ks*32 + q8);
                    bf16x8 b = *(const bf16x8*)(wsb + OFF_W1 + ((nt*2 + ks)*64 + lane)*8);
                    acc = __builtin_amdgcn_mfma_f32_16x16x32_bf16(a, b, acc, 0, 0, 0);
                }
                int col = nt*16 + col16;
                #pragma unroll
                for (int r = 0; r < 4; r++) v1m[(i*16 + ebase + r)*40 + col] = (__bf16)acc[r];
            } else {
                int i = p - 6;
                bf16x8 a = *(const bf16x8*)(vt2 + er*168 + i*32 + q8);
                bf16x8 b = *(const bf16x8*)(wsb + OFF_W2 + lane*8);
                acc = __builtin_amdgcn_mfma_f32_16x16x32_bf16(a, b, acc, 0, 0, 0);
                #pragma unroll
                for (int r = 0; r < 4; r++) v2m[(i*16 + ebase + r)*24 + col16] = (__bf16)acc[r];
            }
        }
    }
    if (t < 128) {
        int ks = t >> 6, l2 = t & 63, e = l2 & 15, o0 = ks*32 + (l2 >> 4)*8;
        bf16x8 v;
        #pragma unroll
        for (int j = 0; j < 8; j++) {
            int o = o0 + j;
            float x = (float)Cb[e*392 + 272 + o] * (float)Cb[e*392 + o];
            v[j] = (__bf16)(x * sigf(x));
        }
        *(bf16x8*)(aSact + t*8) = v;
    }
    for (int idx = t; idx < 544; idx += 256) {
        if (idx < 144) {
            int e = idx / 9, r = idx - e*9, i = r / 3, k = r - i*3;
            const float* d = d1s + e*9;
            e1s[idx] = d[i*3+0]*d[0*3+k] + d[i*3+1]*d[1*3+k] + d[i*3+2]*d[2*3+k];
        } else {
            int j = idx - 144;
            int e = j / 25, r = j - e*25, i = r / 5, k = r - i*5;
            const float* d = d2s + e*25;
            float a = 0.f;
            #pragma unroll
            for (int tt = 0; tt < 5; tt++) a += d[i*5+tt] * d[tt*5+k];
            e2s[j] = a;
        }
    }
    __syncthreads();

    // ---- P3: E-rotation + scale + inline gates -> A-frags ----
    for (int idx = t; idx < 512; idx += 256) {
        if (idx < 192) {
            int i = idx >> 6, l2 = idx & 63, e = l2 & 15, c0 = (l2 >> 4)*8;
            float z0 = e1s[e*9 + i*3], z1 = e1s[e*9 + i*3 + 1], z2 = e1s[e*9 + i*3 + 2];
            bf16x8 m0 = *(const bf16x8*)(v1m + (0*16 + e)*40 + c0);
            bf16x8 m1 = *(const bf16x8*)(v1m + (1*16 + e)*40 + c0);
            bf16x8 m2 = *(const bf16x8*)(v1m + (2*16 + e)*40 + c0);
            bf16x8 s8 = *(const bf16x8*)(Cb + e*392 + 112 + c0);
            bf16x8 gA = *(const bf16x8*)(Cb + e*392 + 336 + c0);
            bf16x8 gB = *(const bf16x8*)(Cb + e*392 + 64 + c0);
            bf16x8 v;
            #pragma unroll
            for (int j = 0; j < 8; j++) {
                float g = sigf((float)gA[j] * (float)gB[j]);
                float a = z0*(float)m0[j] + z1*(float)m1[j] + z2*(float)m2[j];
                v[j] = (__bf16)(g * (float)s8[j] * a);
            }
            *(bf16x8*)(aV1g + idx*8) = v;
        } else {
            int idx2 = idx - 192;
            int i = idx2 >> 6, l2 = idx2 & 63, e = l2 & 15, c0 = (l2 >> 4)*8;
            bf16x8 v;
            if (c0 < 16) {
                const float* ee = e2s + e*25 + i*5;
                float z0 = ee[0], z1 = ee[1], z2 = ee[2], z3 = ee[3], z4 = ee[4];
                bf16x8 m0 = *(const bf16x8*)(v2m + (0*16 + e)*24 + c0);
                bf16x8 m1 = *(const bf16x8*)(v2m + (1*16 + e)*24 + c0);
                bf16x8 m2 = *(const bf16x8*)(v2m + (2*16 + e)*24 + c0);
                bf16x8 m3 = *(const bf16x8*)(v2m + (3*16 + e)*24 + c0);
                bf16x8 m4 = *(const bf16x8*)(v2m + (4*16 + e)*24 + c0);
                bf16x8 s8 = *(const bf16x8*)(Cb + e*392 + 144 + c0);
                bf16x8 gA = *(const bf16x8*)(Cb + e*392 + 368 + c0);
                bf16x8 gB = *(const bf16x8*)(Cb + e*392 + 96 + c0);
                #pragma unroll
                for (int j = 0; j < 8; j++) {
                    float g = sigf((float)gA[j] * (float)gB[j]);
                    float a = z0*(float)m0[j] + z1*(float)m1[j] + z2*(float)m2[j]
                            + z3*(float)m3[j] + z4*(float)m4[j];
                    v[j] = (__bf16)(g * (float)s8[j] * a);
                }
            } else {
                #pragma unroll
                for (int j = 0; j < 8; j++) v[j] = (__bf16)0.0f;
            }
            *(bf16x8*)(aV2g + idx2*8) = v;
        }
    }
    __syncthreads();

    // ---- P4: post GEMMs, env scale -> LDS message tile (or atomic fallback) ----
    {
        int col16 = lane & 15, ebase = (lane >> 4)*4;
        for (int p = wid; p < 15; p += 4) {
            f32x4 acc = {0.f, 0.f, 0.f, 0.f};
            if (p < 4) {
                int nt = p;
                #pragma unroll
                for (int ks = 0; ks < 2; ks++) {
                    bf16x8 a = *(const bf16x8*)(aSact + (ks*64 + lane)*8);
                    bf16x8 b = *(const bf16x8*)(wsb + OFF_PW0 + ((nt*2 + ks)*64 + lane)*8);
                    acc = __builtin_amdgcn_mfma_f32_16x16x32_bf16(a, b, acc, 0, 0, 0);
                }
                int o = nt*16 + col16;
                float bias = pb0[o];
                #pragma unroll
                for (int r = 0; r < 4; r++) {
                    int e = ebase + r;
                    float val = (acc[r] + bias) * (float)Cb[e*392 + 160 + o];
                    if (eidl) mtile[e*248 + o] = (__bf16)val;
                    else      atomicAdd(agg + (size_t)srcs[e]*240 + o, val);
                }
            } else if (p < 10) {
                int q = p - 4, i = q >> 1, nt = q & 1;
                bf16x8 a = *(const bf16x8*)(aV1g + (i*64 + lane)*8);
                bf16x8 b = *(const bf16x8*)(wsb + OFF_PW1 + (nt*64 + lane)*8);
                acc = __builtin_amdgcn_mfma_f32_16x16x32_bf16(a, b, acc, 0, 0, 0);
                int o = nt*16 + col16;
                #pragma unroll
                for (int r = 0; r < 4; r++) {
                    int e = ebase + r;
                    float val = acc[r] * (float)Cb[e*392 + 224 + o];
                    if (eidl) mtile[e*248 + 64 + o*3 + i] = (__bf16)val;
                    else      atomicAdd(agg + (size_t)srcs[e]*240 + 64 + o*3 + i, val);
                }
            } else {
                int i = p - 10;
                bf16x8 a = *(const bf16x8*)(aV2g + (i*64 + lane)*8);
                bf16x8 b = *(const bf16x8*)(wsb + OFF_PW2 + lane*8);
                acc = __builtin_amdgcn_mfma_f32_16x16x32_bf16(a, b, acc, 0, 0, 0);
                #pragma unroll
                for (int r = 0; r < 4; r++) {
                    int e = ebase + r;
                    float val = acc[r] * (float)Cb[e*392 + 256 + col16];
                    if (eidl) mtile[e*248 + 160 + col16*5 + i] = (__bf16)val;
                    else      atomicAdd(agg + (size_t)srcs[e]*240 + 160 + col16*5 + i, val);
                }
            }
        }
    }

    // ---- P5: segmented reduction over the 16 rows -> few coalesced atomics ----
    if (eidl) {
        __syncthreads();
        if (t < 240) {
            float s = 0.f;
            int prev = srcs[0];
            #pragma unroll
            for (int e = 0; e < EB; e++) {
                int sn = srcs[e];           // wave-uniform
                if (sn != prev) {
                    atomicAdd(agg + (size_t)prev*240 + t, s);
                    s = 0.f; prev = sn;
                }
                s += (float)mtile[e*248 + t];
            }
            atomicAdd(agg + (size_t)prev*240 + t, s);
        }
    }
    #undef EIDX
}

// ---------------------------------------------------------------------------
// Node kernel: nsr tile removed (nf read direct in final phase) ->
// LDS 53248 -> 3 blocks/CU (12 waves, was 8).
// ---------------------------------------------------------------------------
__global__ __launch_bounds__(256, 3) void node_kernel(
    const float* __restrict__ nf, const float* __restrict__ mcplg,
    const float* __restrict__ ohg,
    const float* __restrict__ cW1, const float* __restrict__ cb1,
    const float* __restrict__ cW2, const float* __restrict__ cb2,
    const float* __restrict__ gsW, const float* __restrict__ gsb,
    const float* __restrict__ mW1, const float* __restrict__ mb1,
    const float* __restrict__ mW2, const float* __restrict__ mb2,
    const float* __restrict__ lng, const float* __restrict__ lnb,
    const float* __restrict__ rW0, const float* __restrict__ rb0,
    const float* __restrict__ rW1, const float* __restrict__ rW2,
    const float* __restrict__ ohT, float* out0, float* out1)
{
    __shared__ __align__(16) unsigned char pool[53248];
    float* mcp  = (float*)(pool + 0);      // [16][128]
    float* ohv  = (float*)(pool + 8192);   // [16][96]
    float* anew = (float*)(pool + 14336);  // [16][240]
    float* t12  = (float*)(pool + 29696);  // [16][128]
    float* cfg  = (float*)(pool + 37888);  // [16][112]
    float* scm  = (float*)(pool + 45056);  // [16][128]

    const int t  = threadIdx.x;
    const int g  = t >> 7;
    const int o  = t & 127;
    const int nb = g * 8;
    const int n0 = blockIdx.x * NPB;

    for (int idx = t; idx < NPB * 128; idx += 256) {
        int n = idx >> 7, k = idx & 127;
        mcp[n*128 + k] = mcplg[(n0 + n) * 128 + k];
    }
    for (int idx = t; idx < NPB * 96; idx += 256) {
        int n = idx / 96, k = idx - n * 96;
        ohv[n*96 + k] = (k < 95) ? ohg[(n0 + n) * 95 + k] : 0.f;
    }
    for (int idx = t; idx < NPB * 240; idx += 256) {
        int n = idx / 240, k = idx - n * 240;
        anew[n*240 + k] = out0[(n0 + n) * DIM + k];
    }
    __syncthreads();

    {
        float a[8]; float b = cb1[o];
        #pragma unroll
        for (int i = 0; i < 8; i++) a[i] = b;
        #pragma unroll 2
        for (int k4 = 0; k4 < 32; k4++) {
            float w0 = cW1[(4*k4+0)*128 + o], w1 = cW1[(4*k4+1)*128 + o],
                  w2 = cW1[(4*k4+2)*128 + o], w3 = cW1[(4*k4+3)*128 + o];
            #pragma unroll
            for (int i = 0; i < 8; i++) {
                float4 m = *(const float4*)&mcp[(nb+i)*128 + 4*k4];
                a[i] += m.x*w0 + m.y*w1 + m.z*w2 + m.w*w3;
            }
        }
        #pragma unroll
        for (int i = 0; i < 8; i++) { float x = a[i]; t12[(nb+i)*128 + o] = x * sigf(x); }
    }
    __syncthreads();

    if (o < 112) {
        float a[8]; float b = cb2[o];
        #pragma unroll
        for (int i = 0; i < 8; i++) a[i] = b;
        #pragma unroll 2
        for (int k4 = 0; k4 < 32; k4++) {
            float w0 = cW2[(4*k4+0)*112 + o], w1 = cW2[(4*k4+1)*112 + o],
                  w2 = cW2[(4*k4+2)*112 + o], w3 = cW2[(4*k4+3)*112 + o];
            #pragma unroll
            for (int i = 0; i < 8; i++) {
                float4 m = *(const float4*)&t12[(nb+i)*128 + 4*k4];
                a[i] += m.x*w0 + m.y*w1 + m.z*w2 + m.w*w3;
            }
        }
        #pragma unroll
        for (int i = 0; i < 8; i++) cfg[(nb+i)*112 + o] = a[i];
    }
    __syncthreads();

    for (int idx = t; idx < NPB * 240; idx += 256) {
        int n = idx / 240, d = idx - n * 240;
        int ch = (d < 64) ? d : (d < 160 ? 64 + (d - 64) / 3 : 96 + (d - 160) / 5);
        anew[n*240 + d] *= 0.25f * cfg[n*112 + ch];
    }
    __syncthreads();

    {
        float a[8]; float b = gsb[o];
        #pragma unroll
        for (int i = 0; i < 8; i++) a[i] = b;
        #pragma unroll 2
        for (int k4 = 0; k4 < 16; k4++) {
            float w0 = gsW[(4*k4+0)*128 + o], w1 = gsW[(4*k4+1)*128 + o],
                  w2 = gsW[(4*k4+2)*128 + o], w3 = gsW[(4*k4+3)*128 + o];
            #pragma unroll
            for (int i = 0; i < 8; i++) {
                float4 m = *(const float4*)&anew[(nb+i)*240 + 4*k4];
                a[i] += m.x*w0 + m.y*w1 + m.z*w2 + m.w*w3;
            }
        }
        #pragma unroll
        for (int i = 0; i < 8; i++) scm[(nb+i)*128 + o] = a[i];
    }
    __syncthreads();

    {
        float a[8]; float b = mb1[o];
        #pragma unroll
        for (int i = 0; i < 8; i++) a[i] = b;
        #pragma unroll 2
        for (int k4 = 0; k4 < 32; k4++) {
            float w0 = mW1[(4*k4+0)*128 + o], w1 = mW1[(4*k4+1)*128 + o],
                  w2 = mW1[(4*k4+2)*128 + o], w3 = mW1[(4*k4+3)*128 + o];
            #pragma unroll
            for (int i = 0; i < 8; i++) {
                float4 m = *(const float4*)&scm[(nb+i)*128 + 4*k4];
                a[i] += m.x*w0 + m.y*w1 + m.z*w2 + m.w*w3;
            }
        }
        #pragma unroll 2
        for (int k4 = 0; k4 < 32; k4++) {
            float w0 = mW1[(128+4*k4+0)*128 + o], w1 = mW1[(128+4*k4+1)*128 + o],
                  w2 = mW1[(128+4*k4+2)*128 + o], w3 = mW1[(128+4*k4+3)*128 + o];
            #pragma unroll
            for (int i = 0; i < 8; i++) {
                float4 m = *(const float4*)&mcp[(nb+i)*128 + 4*k4];
                a[i] += m.x*w0 + m.y*w1 + m.z*w2 + m.w*w3;
            }
        }
        #pragma unroll
        for (int i = 0; i < 8; i++) { float x = a[i]; t12[(nb+i)*128 + o] = x * sigf(x); }
    }
    __syncthreads();

    {
        float a[8]; float b = mb2[o];
        #pragma unroll
        for (int i = 0; i < 8; i++) a[i] = b;
        #pragma unroll 2
        for (int k4 = 0; k4 < 32; k4++) {
            float w0 = mW2[(4*k4+0)*128 + o], w1 = mW2[(4*k4+1)*128 + o],
                  w2 = mW2[(4*k4+2)*128 + o], w3 = mW2[(4*k4+3)*128 + o];
            #pragma unroll
            for (int i = 0; i < 8; i++) {
                float4 m = *(const float4*)&t12[(nb+i)*128 + 4*k4];
                a[i] += m.x*w0 + m.y*w1 + m.z*w2 + m.w*w3;
            }
        }
        #pragma unroll
        for (int i = 0; i < 8; i++) scm[(nb+i)*128 + o] = mcp[(nb+i)*128 + o] + a[i];
    }
    __syncthreads();

    {
        int n = t >> 4, l = t & 15;
        float x[8]; float s = 0.f, ss = 0.f;
        #pragma unroll
        for (int i = 0; i < 8; i++) { x[i] = scm[n*128 + l + 16*i]; s += x[i]; ss += x[i]*x[i]; }
        #pragma unroll
        for (int off = 8; off > 0; off >>= 1) {
            s  += __shfl_down(s,  off, 16);
            ss += __shfl_down(ss, off, 16);
        }
        s  = __shfl(s, 0, 16);
        ss = __shfl(ss, 0, 16);
        float mu   = s * (1.f / 128.f);
        float var  = ss * (1.f / 128.f) - mu * mu;
        float rstd = rsqrtf(var + 1e-5f);
        float* op = out1 + (n0 + n) * 128;
        #pragma unroll
        for (int i = 0; i < 8; i++) {
            int c = l + 16*i;
            op[c] = (x[i] - mu) * rstd * lng[c] + lnb[c];
        }
    }

    if (o < 112) {
        float a[8] = {0.f,0.f,0.f,0.f,0.f,0.f,0.f,0.f};
        #pragma unroll 2
        for (int k4 = 0; k4 < 24; k4++) {
            float w0 = ohT[(4*k4+0)*112 + o], w1 = ohT[(4*k4+1)*112 + o],
                  w2 = ohT[(4*k4+2)*112 + o], w3 = ohT[(4*k4+3)*112 + o];
            #pragma unroll
            for (int i = 0; i < 8; i++) {
                float4 m = *(const float4*)&ohv[(nb+i)*96 + 4*k4];
                a[i] += m.x*w0 + m.y*w1 + m.z*w2 + m.w*w3;
            }
        }
        #pragma unroll
        for (int i = 0; i < 8; i++) cfg[(nb+i)*112 + o] = a[i];
    }
    __syncthreads();

    const float c_new = 0.4472135955f;
    const float c_old = 0.8944271910f;
    for (int idx = t; idx < NPB * 240; idx += 256) {
        int n = idx / 240, d = idx - n * 240;
        const float* nrow = nf + (size_t)(n0 + n) * DIM;
        float res, gg;
        if (d < 64) {
            float acc = rb0[d];
            #pragma unroll 4
            for (int c = 0; c < 64; c++) acc += nrow[c] * rW0[c * 64 + d];
            res = acc; gg = cfg[n*112 + d];
        } else if (d < 160) {
            int dd = d - 64, oo = dd / 3, j = dd - oo * 3;
            float acc = 0.f;
            #pragma unroll 4
            for (int c = 0; c < 32; c++) acc += nrow[64 + c*3 + j] * rW1[c * 32 + oo];
            res = acc; gg = cfg[n*112 + 64 + oo];
        } else {
            int dd = d - 160, oo = dd / 5, j = dd - oo * 5;
            float acc = 0.f;
            #pragma unroll 4
            for (int c = 0; c < 16; c++) acc += nrow[160 + c*5 + j] * rW2[c * 16 + oo];
            res = acc; gg = cfg[n*112 + 96 + oo];
        }
        float v = c_new * anew[n*240 + d] + c_old * res;
        out0[(n0 + n) * DIM + d] = v * (1.f + gg);
    }
}

extern "C" void kernel_launch(void* const* d_in, const int* in_sizes, int n_in,
                              void* d_out, int out_size, void* d_ws, size_t ws_size,
                              hipStream_t stream) {
    const float* nf      = (const float*)d_in[0];
    const float* ef      = (const float*)d_in[1];
    const float* lat     = (const float*)d_in[2];
    const float* mcpl    = (const float*)d_in[3];
    const float* ohot    = (const float*)d_in[4];
    const float* D1      = (const float*)d_in[5];
    const float* D2      = (const float*)d_in[6];
    const float* so2_W0  = (const float*)d_in[7];
    const float* so2_W1  = (const float*)d_in[8];
    const float* so2_W2  = (const float*)d_in[9];
    const float* so2_Ws  = (const float*)d_in[10];
    const float* env_W   = (const float*)d_in[11];
    const float* post_W0 = (const float*)d_in[12];
    const float* post_b0 = (const float*)d_in[13];
    const float* post_W1 = (const float*)d_in[14];
    const float* post_W2 = (const float*)d_in[15];
    const float* res_W0  = (const float*)d_in[16];
    const float* res_b0  = (const float*)d_in[17];
    const float* res_W1  = (const float*)d_in[18];
    const float* res_W2  = (const float*)d_in[19];
    const float* cpl_W1  = (const float*)d_in[20];
    const float* cpl_b1  = (const float*)d_in[21];
    const float* cpl_W2  = (const float*)d_in[22];
    const float* cpl_b2  = (const float*)d_in[23];
    const float* gs_W    = (const float*)d_in[24];
    const float* gs_b    = (const float*)d_in[25];
    const float* msg_W1  = (const float*)d_in[26];
    const float* msg_b1  = (const float*)d_in[27];
    const float* msg_W2  = (const float*)d_in[28];
    const float* msg_b2  = (const float*)d_in[29];
    const float* ln_g    = (const float*)d_in[30];
    const float* ln_b    = (const float*)d_in[31];
    const float* oh_w0   = (const float*)d_in[32];
    const float* oh_w1   = (const float*)d_in[33];
    const float* oh_w2   = (const float*)d_in[34];
    const int*   eidx    = (const int*)d_in[35];   // (2,E); row 0 = src

    float* out0 = (float*)d_out;                     // N*DIM, doubles as agg
    float* out1 = (float*)d_out + (size_t)NN * DIM;  // N*CPL
    char*   wsB = (char*)d_ws;
    __bf16* wsb = (__bf16*)d_ws;
    float*  ohT = (float*)(wsB + OHT_BYTE_OFF);

    const size_t needA = (size_t)EID_BYTE_OFF + (size_t)NE * sizeof(int);
    const bool planA = ws_size >= needA;

    (void)hipMemsetAsync(out0, 0, (size_t)NN * DIM * sizeof(float), stream);

    if (planA) {
        int* cnt  = (int*)(wsB + CNT_BYTE_OFF);
        int* row  = (int*)(wsB + ROW_BYTE_OFF);
        int* cur  = (int*)(wsB + CUR_BYTE_OFF);
        int* eidl = (int*)(wsB + EID_BYTE_OFF);

        (void)hipMemsetAsync(cnt, 0, 10240 * sizeof(int), stream);
        prep_kernel<<<56 + (NE + 255) / 256, 256, 0, stream>>>(
            so2_Ws, env_W, so2_W0, so2_W1, so2_W2, post_W0, post_W1, post_W2,
            oh_w0, oh_w1, oh_w2, wsb, ohT, eidx, cnt);
        scan_kernel<<<1, 256, 0, stream>>>(cnt, row, cur);
        fill_kernel<<<(NE + 255) / 256, 256, 0, stream>>>(eidx, cur, eidl);

        edge_mfma_kernel<<<NE / EB, 256, 0, stream>>>(
            nf, ef, lat, D1, D2, post_b0, eidx, eidl, wsb, out0);
    } else {
        prep_kernel<<<56, 256, 0, stream>>>(
            so2_Ws, env_W, so2_W0, so2_W1, so2_W2, post_W0, post_W1, post_W2,
            oh_w0, oh_w1, oh_w2, wsb, ohT, eidx, nullptr);
        edge_mfma_kernel<<<NE / EB, 256, 0, stream>>>(
            nf, ef, lat, D1, D2, post_b0, eidx, nullptr, wsb, out0);
    }

    node_kernel<<<NN / NPB, 256, 0, stream>>>(
        nf, mcpl, ohot, cpl_W1, cpl_b1, cpl_W2, cpl_b2, gs_W, gs_b,
        msg_W1, msg_b1, msg_W2, msg_b2, ln_g, ln_b,
        res_W0, res_b0, res_W1, res_W2, ohT, out0, out1);
}